// Round 10
// baseline (829.838 us; speedup 1.0000x reference)
//
#include <hip/hip_runtime.h>
#include <cstdint>
#include <cstddef>

#define NN 131072
#define EE 524288
#define BB 4096
#define LL 768

typedef __attribute__((ext_vector_type(8))) short bf16x8;
typedef __attribute__((ext_vector_type(4))) float f32x4;
typedef __attribute__((ext_vector_type(2))) unsigned int uint2v;

// ---------- helpers ----------
__device__ __forceinline__ float b2f(unsigned short u) {
  return __uint_as_float(((unsigned int)u) << 16);
}
__device__ __forceinline__ unsigned short f2b(float f) {
  unsigned int x = __float_as_uint(f);
  x += 0x7fff + ((x >> 16) & 1);  // RNE
  return (unsigned short)(x >> 16);
}
__device__ __forceinline__ unsigned f2b2(float lo, float hi) {
#if __has_builtin(__builtin_amdgcn_cvt_pk_bf16_f32)
  typedef __attribute__((ext_vector_type(2))) __bf16 bf16v2;
  bf16v2 r = __builtin_amdgcn_cvt_pk_bf16_f32(lo, hi);
  return __builtin_bit_cast(unsigned, r);
#else
  return (unsigned)f2b(lo) | ((unsigned)f2b(hi) << 16);
#endif
}
__device__ __forceinline__ float sigm(float x) { return 1.f / (1.f + expf(-x)); }
__device__ __forceinline__ float softplus_(float x) {
  return fmaxf(x, 0.f) + log1pf(expf(-fabsf(x)));
}

// ---------- CSR build ----------
__global__ __launch_bounds__(256) void k_zeroi(int* __restrict__ p) {
  p[blockIdx.x * 256 + threadIdx.x] = 0;
}
__global__ __launch_bounds__(256) void k_hist(const int* __restrict__ ei,
                                              int* __restrict__ degi) {
  int e = blockIdx.x * 256 + threadIdx.x;
  atomicAdd(&degi[ei[EE + e]], 1);
}
__global__ __launch_bounds__(256) void k_dinv(const int* __restrict__ degi,
                                              float* __restrict__ d) {
  int i = blockIdx.x * 256 + threadIdx.x;
  d[i] = rsqrtf((float)degi[i] + 1.0f);
}
__global__ __launch_bounds__(256) void k_scan1(const int* __restrict__ degi,
                                               int* __restrict__ incl,
                                               int* __restrict__ bsum) {
  __shared__ int s[256];
  int t = threadIdx.x;
  int i = blockIdx.x * 256 + t;
  s[t] = degi[i];
  __syncthreads();
  for (int off = 1; off < 256; off <<= 1) {
    int u = (t >= off) ? s[t - off] : 0;
    __syncthreads();
    s[t] += u;
    __syncthreads();
  }
  incl[i] = s[t];
  if (t == 255) bsum[blockIdx.x] = s[t];
}
__global__ __launch_bounds__(512) void k_scan2(const int* __restrict__ bsum,
                                               int* __restrict__ bexcl) {
  __shared__ int s[512];
  int t = threadIdx.x;
  s[t] = bsum[t];
  __syncthreads();
  int orig = s[t];
  for (int off = 1; off < 512; off <<= 1) {
    int u = (t >= off) ? s[t - off] : 0;
    __syncthreads();
    s[t] += u;
    __syncthreads();
  }
  bexcl[t] = s[t] - orig;
}
__global__ __launch_bounds__(256) void k_scan3(const int* __restrict__ incl,
                                               const int* __restrict__ degi,
                                               const int* __restrict__ bexcl,
                                               int* __restrict__ offs) {
  int t = threadIdx.x;
  int i = blockIdx.x * 256 + t;
  offs[i] = incl[i] - degi[i] + bexcl[blockIdx.x];
  if (i == 0) offs[NN] = EE;
}
__global__ __launch_bounds__(256) void k_scatter(const int* __restrict__ ei,
                                                 const int* __restrict__ offs,
                                                 int* __restrict__ cur,
                                                 int* __restrict__ csr) {
  int e = blockIdx.x * 256 + threadIdx.x;
  int dst = ei[EE + e];
  int pos = atomicAdd(&cur[dst], 1);
  csr[offs[dst] + pos] = ei[e];
}

// ---------- GCN (bf16 feature buffers) ----------
__global__ __launch_bounds__(256) void k_mm1(const float* __restrict__ drug,
                                             const float* __restrict__ W,
                                             const float* __restrict__ dinv,
                                             unsigned short* __restrict__ g) {
  __shared__ float Ws[9 * 64];
  int t = threadIdx.x;
  for (int i = t; i < 576; i += 256) Ws[i] = W[i];
  __syncthreads();
  int node = blockIdx.x * 4 + (t >> 6);
  int f = t & 63;
  const float* dr = drug + (size_t)node * 9;
  float s = 0.f;
#pragma unroll
  for (int k = 0; k < 9; k++) s += dr[k] * Ws[k * 64 + f];
  g[(size_t)node * 64 + f] = f2b(dinv[node] * s);
}

template <bool TANH>
__global__ __launch_bounds__(256) void k_layer(const unsigned short* __restrict__ gin,
                                               const int* __restrict__ offs,
                                               const int* __restrict__ csr,
                                               const float* __restrict__ dinv,
                                               const float* __restrict__ bias,
                                               const float* __restrict__ W,
                                               unsigned short* __restrict__ outb) {
  __shared__ float Ws[64 * 64];
  __shared__ float xs[4][64];
  const int t = threadIdx.x;
  for (int i = t; i < 4096; i += 256) Ws[i] = W[i];
  const int d = blockIdx.x * 4 + (t >> 6);
  const int f = t & 63;
  const float di = dinv[d];
  const int j0 = offs[d], j1 = offs[d + 1];
  float acc = b2f(gin[(size_t)d * 64 + f]);
  int j = j0;
  for (; j + 4 <= j1; j += 4) {
    int s0 = csr[j], s1 = csr[j + 1], s2 = csr[j + 2], s3 = csr[j + 3];
    float v0 = b2f(gin[(size_t)s0 * 64 + f]);
    float v1 = b2f(gin[(size_t)s1 * 64 + f]);
    float v2 = b2f(gin[(size_t)s2 * 64 + f]);
    float v3 = b2f(gin[(size_t)s3 * 64 + f]);
    acc += (v0 + v1) + (v2 + v3);
  }
  for (; j < j1; j++) acc += b2f(gin[(size_t)csr[j] * 64 + f]);
  float v = di * acc + bias[f];
  if (TANH) v = tanhf(v);
  xs[t >> 6][f] = v;
  __syncthreads();
  const float* xr = xs[t >> 6];
  float s = 0.f;
#pragma unroll
  for (int k = 0; k < 64; k++) s += xr[k] * Ws[k * 64 + f];
  outb[(size_t)d * 64 + f] = f2b(di * s);
}

__global__ __launch_bounds__(512) void k_lastpool(const unsigned short* __restrict__ gin,
                                                  const int* __restrict__ offs,
                                                  const int* __restrict__ csr,
                                                  const float* __restrict__ dinv,
                                                  const float* __restrict__ bias,
                                                  float* __restrict__ pooled) {
  __shared__ float smax[8][64], ssum[8][64];
  const int t = threadIdx.x;
  const int f = t & 63, grp = t >> 6;
  const int g = blockIdx.x;
  const float bf = bias[f];
  float mx = -1e30f, sm = 0.f;
#pragma unroll
  for (int i = 0; i < 4; i++) {
    int d = g * 32 + grp * 4 + i;
    const float di = dinv[d];
    const int j0 = offs[d], j1 = offs[d + 1];
    float acc = b2f(gin[(size_t)d * 64 + f]);
    int j = j0;
    for (; j + 4 <= j1; j += 4) {
      int s0 = csr[j], s1 = csr[j + 1], s2 = csr[j + 2], s3 = csr[j + 3];
      acc += (b2f(gin[(size_t)s0 * 64 + f]) + b2f(gin[(size_t)s1 * 64 + f]))
           + (b2f(gin[(size_t)s2 * 64 + f]) + b2f(gin[(size_t)s3 * 64 + f]));
    }
    for (; j < j1; j++) acc += b2f(gin[(size_t)csr[j] * 64 + f]);
    float v = di * acc + bf;
    mx = fmaxf(mx, v);
    sm += v;
  }
  smax[grp][f] = mx;
  ssum[grp][f] = sm;
  __syncthreads();
  if (t < 64) {
    float m = smax[0][t], s = ssum[0][t];
#pragma unroll
    for (int w = 1; w < 8; w++) { m = fmaxf(m, smax[w][t]); s += ssum[w][t]; }
    pooled[(size_t)g * 128 + t] = m;
    pooled[(size_t)g * 128 + 64 + t] = s * (1.f / 32.f);
  }
}

// gout(bf16): 8 graphs/block, 512 blocks (2/CU)
__global__ __launch_bounds__(256) void k_outmm(const float* __restrict__ pooled,
                                               const float* __restrict__ W,
                                               const float* __restrict__ bias,
                                               unsigned short* __restrict__ gout) {
  __shared__ float ps[8][128];
  int t = threadIdx.x;
  int g0 = blockIdx.x * 8;
  for (int i = t; i < 8 * 128; i += 256) ps[i >> 7][i & 127] = pooled[(size_t)g0 * 128 + i];
  __syncthreads();
  float a0[8], a1[8], a2[8];
#pragma unroll
  for (int j = 0; j < 8; j++) { a0[j] = 0.f; a1[j] = 0.f; a2[j] = 0.f; }
  for (int k = 0; k < 128; k++) {
    float w0 = W[k * 768 + t];
    float w1 = W[k * 768 + t + 256];
    float w2 = W[k * 768 + t + 512];
#pragma unroll
    for (int j = 0; j < 8; j++) {
      float p = ps[j][k];
      a0[j] += p * w0; a1[j] += p * w1; a2[j] += p * w2;
    }
  }
  float b0 = bias[t], b1 = bias[t + 256], b2 = bias[t + 512];
  for (int j = 0; j < 8; j++) {
    gout[(size_t)(g0 + j) * 768 + t]       = f2b(a0[j] + b0);
    gout[(size_t)(g0 + j) * 768 + t + 256] = f2b(a1[j] + b1);
    gout[(size_t)(g0 + j) * 768 + t + 512] = f2b(a2[j] + b2);
  }
}

// ---------- composite conv precompute ----------
__global__ __launch_bounds__(512) void k_prepk7(
    const float* __restrict__ W1, const float* __restrict__ b1,
    const float* __restrict__ W2, const float* __restrict__ b2,
    const float* __restrict__ W3, const float* __restrict__ b3,
    float* __restrict__ Kc, float* __restrict__ bconst) {
  __shared__ float W1s[192], W2s[3072], W3s[3072];
  __shared__ float b1s[32], b2s[32], b3s[32];
  __shared__ float M[320];
  __shared__ float beta[32];
  const int t = threadIdx.x;
  for (int i = t; i < 3072; i += 512) { W2s[i] = W2[i]; W3s[i] = W3[i]; }
  if (t < 192) W1s[t] = W1[t];
  if (t >= 192 && t < 224) { int i = t - 192; b1s[i] = b1[i]; b2s[i] = b2[i]; b3s[i] = b3[i]; }
  __syncthreads();
  if (t < 320) {
    int i = t / 10, rem = t % 10, c = rem / 5, t12 = rem % 5;
    float s = 0.f;
    for (int j = 0; j < 32; j++)
#pragma unroll
      for (int t2 = 0; t2 < 3; t2++) {
        int t1 = t12 - t2;
        if (t1 >= 0 && t1 < 3) s += W2s[(i * 32 + j) * 3 + t2] * W1s[(j * 2 + c) * 3 + t1];
      }
    M[i * 10 + c * 5 + t12] = s;
  }
  if (t >= 384 && t < 416) {
    int i = t - 384;
    float s = b2s[i];
    for (int j = 0; j < 32; j++) {
      float w = W2s[(i * 32 + j) * 3] + W2s[(i * 32 + j) * 3 + 1] + W2s[(i * 32 + j) * 3 + 2];
      s += w * b1s[j];
    }
    beta[i] = s;
  }
  __syncthreads();
  if (t < 448) {
    int o = t / 14, rem = t % 14, c = rem / 7, tt = rem % 7;
    float s = 0.f;
    for (int i = 0; i < 32; i++)
#pragma unroll
      for (int t3 = 0; t3 < 3; t3++) {
        int t12 = tt - t3;
        if (t12 >= 0 && t12 < 5) s += W3s[(o * 32 + i) * 3 + t3] * M[i * 10 + c * 5 + t12];
      }
    Kc[o * 14 + c * 7 + tt] = s;
  }
  if (t >= 480 && t < 512) {
    int o = t - 480;
    float s = b3s[o];
    for (int i = 0; i < 32; i++) {
      float w = W3s[(o * 32 + i) * 3] + W3s[(o * 32 + i) * 3 + 1] + W3s[(o * 32 + i) * 3 + 2];
      s += w * beta[i];
    }
    bconst[o] = s;
  }
}

__global__ __launch_bounds__(64) void k_prepedge(
    const float* __restrict__ W1, const float* __restrict__ b1,
    const float* __restrict__ W2, const float* __restrict__ b2,
    const float* __restrict__ W3, const float* __restrict__ b3,
    float* __restrict__ edgeK, float* __restrict__ edgeB) {
  __shared__ float W1s[192], W2s[3072], W3s[3072];
  __shared__ float b1s[32], b2s[32], b3s[32];
  __shared__ float cl[2][6], h1[32][5], h2[32][4];
  const int t = threadIdx.x;
  const int side = blockIdx.x / 13, run = blockIdx.x % 13;
  for (int i = t; i < 3072; i += 64) { W2s[i] = W2[i]; W3s[i] = W3[i]; }
  for (int i = t; i < 192; i += 64) W1s[i] = W1[i];
  if (t < 32) { b1s[t] = b1[t]; b2s[t] = b2[t]; b3s[t] = b3[t]; }
  if (t < 12) cl[t / 6][t % 6] = (run == t) ? 1.f : 0.f;
  __syncthreads();
  const bool ub = (run == 12);
  if (t < 32) {
    int i = t;
    for (int p = 0; p < 5; p++) {
      float s = ub ? b1s[i] : 0.f;
      for (int c = 0; c < 2; c++)
#pragma unroll
        for (int tau = 0; tau < 3; tau++) {
          int x = (side == 0) ? (p + tau - 1) : (p + tau);
          if (x >= 0 && x < 6) s += W1s[(i * 2 + c) * 3 + tau] * cl[c][x];
        }
      h1[i][p] = s;
    }
  }
  __syncthreads();
  if (t < 32) {
    int o = t;
    for (int u = 0; u < 4; u++) {
      float s = ub ? b2s[o] : 0.f;
      for (int i = 0; i < 32; i++)
#pragma unroll
        for (int tau = 0; tau < 3; tau++) {
          int q = (side == 0) ? (u + tau - 1) : (u + tau);
          if (q >= 0 && q < 5) s += W2s[(o * 32 + i) * 3 + tau] * h1[i][q];
        }
      h2[o][u] = s;
    }
  }
  __syncthreads();
  if (t < 32) {
    int o = t;
    for (int e = 0; e < 2; e++) {
      float s = ub ? b3s[o] : 0.f;
      for (int i = 0; i < 32; i++)
#pragma unroll
        for (int tau = 0; tau < 3; tau++) {
          int u = (side == 0) ? (e + tau - 1) : (e + tau + 1);
          if (u >= 0 && u < 4) s += W3s[(o * 32 + i) * 3 + tau] * h2[i][u];
        }
      int slot = (side * 2 + e) * 32 + o;
      if (ub) edgeB[slot] = s;
      else edgeK[slot * 12 + run] = s;
    }
  }
}

// Wbv[k*32+o] bf16 for the VALU mlp: k = pv index (lp*32+ch), korig = ch*384+lp
__global__ __launch_bounds__(256) void k_prepwv(const float* __restrict__ W,
                                                unsigned short* __restrict__ Wbv) {
  int idx = blockIdx.x * 256 + threadIdx.x;  // 0 .. 393215
  int o = idx & 31;
  int p_idx = idx >> 5;
  int ch = p_idx & 31, lp = p_idx >> 5;
  Wbv[idx] = f2b(W[(size_t)o * 12288 + ch * 384 + lp]);
}

// ---------- fused CNN chain + CBAM + maxpool + MLP layer-1 ----------
__global__ __launch_bounds__(512) void k_cnn(
    const unsigned short* __restrict__ gout, const float* __restrict__ protein,
    const float* __restrict__ Kc, const float* __restrict__ bconst,
    const float* __restrict__ edgeK, const float* __restrict__ edgeB,
    const float* __restrict__ caW1, const float* __restrict__ caW2,
    const float* __restrict__ samW, const float* __restrict__ samb,
    const unsigned short* __restrict__ Wbv, float* __restrict__ partial) {
  __shared__ float combf[2][776];    // comb[c][l+4], zero outside [0,768)
  __shared__ float K7s[448];
  __shared__ float bcs[32];
  __shared__ float xbuf[2320];       // xm@0, xM@772, att@1544
  __shared__ alignas(8) unsigned short pv[12288];  // pooled vector, bf16
  __shared__ float wmaxs[8][32], wsums[8][32];
  __shared__ float cmaxs[32], csums[32], t1buf[2][16], feats[32], samWs[8];
  __shared__ float wred[8][4][8];
  const int t = threadIdx.x;
  const int b = blockIdx.x;
  const int lane = t & 63, wv = t >> 6, lx = lane & 15, quad = lane >> 4;

  // S0: stage
  for (int i = t; i < 1552; i += 512) {
    int c = i / 776, li = i - c * 776;
    int l = li - 4;
    float v = 0.f;
    if (l >= 0 && l < LL)
      v = c ? protein[(size_t)b * LL + l] : b2f(gout[(size_t)b * LL + l]);
    combf[c][li] = v;
  }
  if (t < 448) K7s[t] = Kc[t];
  if (t >= 448 && t < 480) bcs[t - 448] = bconst[t - 448];
  if (t >= 480 && t < 486) samWs[t - 480] = samW[t - 480];
  if (t == 486) samWs[6] = samb[0];
  __syncthreads();

  // S1: composite 7-tap conv -> a3[n][mt] registers
  f32x4 a3[6][2];
#pragma unroll
  for (int mt = 0; mt < 2; mt++) {
    float kr[4][14];
#pragma unroll
    for (int r = 0; r < 4; r++) {
      int o = mt * 16 + quad * 4 + r;
#pragma unroll
      for (int q = 0; q < 14; q++) kr[r][q] = K7s[o * 14 + q];
    }
#pragma unroll
    for (int n = 0; n < 6; n++) {
      int l = (wv * 6 + n) * 16 + lx;
      float w0[7], w1[7];
#pragma unroll
      for (int q = 0; q < 7; q++) { w0[q] = combf[0][l + 1 + q]; w1[q] = combf[1][l + 1 + q]; }
#pragma unroll
      for (int r = 0; r < 4; r++) {
        float s = bcs[mt * 16 + quad * 4 + r];
#pragma unroll
        for (int q = 0; q < 7; q++) s += kr[r][q] * w0[q] + kr[r][7 + q] * w1[q];
        a3[n][mt][r] = s;
      }
    }
  }
  // edge fixup: l in {0,1} and {766,767}
  {
    bool left = (wv == 0 && lx < 2);
    bool right = (wv == 7 && lx >= 14);
    if (left || right) {
      int n = left ? 0 : 5;
      int e = left ? lx : (lx - 14);
      int side = left ? 0 : 1;
      int cbase = left ? 4 : 766;
#pragma unroll
      for (int mt = 0; mt < 2; mt++)
#pragma unroll
        for (int r = 0; r < 4; r++) {
          int o = mt * 16 + quad * 4 + r;
          int slot = (side * 2 + e) * 32 + o;
          float s = edgeB[slot];
          const float* ek = &edgeK[slot * 12];
#pragma unroll
          for (int w = 0; w < 6; w++)
            s += ek[w] * combf[0][cbase + w] + ek[6 + w] * combf[1][cbase + w];
          a3[n][mt][r] = s;
        }
    }
  }

  // S3: channel stats
  float tmax[2][4], tsum[2][4];
#pragma unroll
  for (int mt = 0; mt < 2; mt++)
#pragma unroll
    for (int r = 0; r < 4; r++) { tmax[mt][r] = -1e30f; tsum[mt][r] = 0.f; }
#pragma unroll
  for (int n = 0; n < 6; n++)
#pragma unroll
    for (int mt = 0; mt < 2; mt++)
#pragma unroll
      for (int r = 0; r < 4; r++) {
        float v = a3[n][mt][r];
        tmax[mt][r] = fmaxf(tmax[mt][r], v);
        tsum[mt][r] += v;
      }
#pragma unroll
  for (int mt = 0; mt < 2; mt++)
#pragma unroll
    for (int r = 0; r < 4; r++) {
      float m = tmax[mt][r], s = tsum[mt][r];
      for (int d = 1; d < 16; d <<= 1) {
        m = fmaxf(m, __shfl_xor(m, d));
        s += __shfl_xor(s, d);
      }
      if (lx == 0) {
        wmaxs[wv][mt * 16 + quad * 4 + r] = m;
        wsums[wv][mt * 16 + quad * 4 + r] = s;
      }
    }
  __syncthreads();

  // S4: cross-wave stats + channel-attention MLP
  if (t < 32) {
    float m = wmaxs[0][t], s = wsums[0][t];
#pragma unroll
    for (int w = 1; w < 8; w++) { m = fmaxf(m, wmaxs[w][t]); s += wsums[w][t]; }
    cmaxs[t] = m;
    csums[t] = s;
  }
  __syncthreads();
  if (t < 32) {
    int j = t & 15;
    int mean = t >> 4;
    float s = 0.f;
    for (int o = 0; o < 32; o++) {
      float v = mean ? csums[o] * (1.f / 768.f) : cmaxs[o];
      s += v * caW1[j * 32 + o];
    }
    t1buf[mean][j] = s;
  }
  __syncthreads();
  if (t < 32) {
    float m1 = 0.f, m2 = 0.f;
    for (int j = 0; j < 16; j++) {
      m1 += t1buf[0][j] * caW2[t * 16 + j];
      m2 += t1buf[1][j] * caW2[t * 16 + j];
    }
    feats[t] = sigm(fmaxf(m1, 0.f) + fmaxf(m2, 0.f));
  }
  __syncthreads();

  // S5: spatial stats from registers
  float frq[2][4];
#pragma unroll
  for (int mt = 0; mt < 2; mt++)
#pragma unroll
    for (int r = 0; r < 4; r++) frq[mt][r] = feats[mt * 16 + quad * 4 + r];
#pragma unroll
  for (int n = 0; n < 6; n++) {
    int l = (wv * 6 + n) * 16 + lx;
    float sm = 0.f, mx = -1e30f;
#pragma unroll
    for (int mt = 0; mt < 2; mt++)
#pragma unroll
      for (int r = 0; r < 4; r++) {
        float v = a3[n][mt][r] * frq[mt][r];
        sm += v;
        mx = fmaxf(mx, v);
      }
    sm += __shfl_xor(sm, 16); mx = fmaxf(mx, __shfl_xor(mx, 16));
    sm += __shfl_xor(sm, 32); mx = fmaxf(mx, __shfl_xor(mx, 32));
    if (quad == 0) {
      xbuf[l] = sm * (1.f / 32.f);
      xbuf[772 + l] = mx;
    }
  }
  __syncthreads();

  // S6: spatial attention conv + sigmoid
  for (int l = t; l < LL; l += 512) {
    float a = samWs[6];
#pragma unroll
    for (int k = 0; k < 3; k++) {
      int ll = l + k - 1;
      float vm = (ll >= 0 && ll < LL) ? xbuf[ll] : 0.f;
      float vM = (ll >= 0 && ll < LL) ? xbuf[772 + ll] : 0.f;
      a += samWs[k] * vm + samWs[3 + k] * vM;
    }
    xbuf[1544 + l] = sigm(a);
  }
  __syncthreads();

  // S7: scale + maxpool2 via lane-pair shuffle -> pv in LDS (bf16)
#pragma unroll
  for (int n = 0; n < 6; n++) {
    int l = (wv * 6 + n) * 16 + lx;
    float at = xbuf[1544 + l];
    float m[2][4];
#pragma unroll
    for (int mt = 0; mt < 2; mt++)
#pragma unroll
      for (int r = 0; r < 4; r++) {
        float v = a3[n][mt][r] * frq[mt][r] * at;
        m[mt][r] = fmaxf(v, __shfl_xor(v, 1));
      }
    if (!(lx & 1)) {
      int lp = l >> 1;
#pragma unroll
      for (int mt = 0; mt < 2; mt++) {
        uint2v pk;
        pk.x = f2b2(m[mt][0], m[mt][1]);
        pk.y = f2b2(m[mt][2], m[mt][3]);
        *(uint2v*)&pv[lp * 32 + mt * 16 + quad * 4] = pk;
      }
    }
  }
  __syncthreads();

  // S8: MLP layer-1 for this graph: pv[12288] @ W1 -> partial[b][32].
  // lane = og(2b) | klow(4b); wave covers K-range wv*1536..+1536; global reads
  // are 1 KB contiguous per wave-instruction.
  {
    const int og = lane & 3, klow = (lane >> 2) & 15;
    float acc[8];
#pragma unroll
    for (int j = 0; j < 8; j++) acc[j] = 0.f;
    const int kbase = wv * 1536 + klow;
#pragma unroll 4
    for (int i = 0; i < 96; i++) {
      int k = kbase + i * 16;
      float v = b2f(pv[k]);
      bf16x8 w = *(const bf16x8*)&Wbv[(size_t)k * 32 + og * 8];
#pragma unroll
      for (int j = 0; j < 8; j++) acc[j] += v * b2f((unsigned short)w[j]);
    }
#pragma unroll
    for (int j = 0; j < 8; j++) {
      acc[j] += __shfl_xor(acc[j], 4);
      acc[j] += __shfl_xor(acc[j], 8);
      acc[j] += __shfl_xor(acc[j], 16);
      acc[j] += __shfl_xor(acc[j], 32);
    }
    if (klow == 0)
#pragma unroll
      for (int j = 0; j < 8; j++) wred[wv][og][j] = acc[j];
  }
  __syncthreads();
  if (t < 32) {
    float s = 0.f;
#pragma unroll
    for (int w = 0; w < 8; w++) s += wred[w][t >> 3][t & 7];
    partial[(size_t)b * 32 + t] = s;
  }
}

// MLP tail: bias + softplus chain + layers 2,3.
__global__ __launch_bounds__(512) void k_mlp2(
    const float* __restrict__ partial,
    const float* __restrict__ lb1, const float* __restrict__ W2,
    const float* __restrict__ lb2, const float* __restrict__ W3,
    const float* __restrict__ lb3, float* __restrict__ out) {
  __shared__ float s1[16][32];
  __shared__ float s2[16][32];
  const int t = threadIdx.x;
  const int g0 = blockIdx.x * 16;
  {
    int g = t >> 5, o = t & 31;
    float s = lb1[o] + partial[(size_t)(g0 + g) * 32 + o];
    s1[g][o] = softplus_(s);
  }
  __syncthreads();
  {
    int g = t >> 5, o = t & 31;
    float s = lb2[o];
    for (int kk = 0; kk < 32; kk++) s += s1[g][kk] * W2[o * 32 + kk];
    s2[g][o] = softplus_(s);
  }
  __syncthreads();
  if (t < 16) {
    float s = lb3[0];
    for (int kk = 0; kk < 32; kk++) s += s2[t][kk] * W3[kk];
    out[g0 + t] = softplus_(s);
  }
}

extern "C" void kernel_launch(void* const* d_in, const int* in_sizes, int n_in,
                              void* d_out, int out_size, void* d_ws, size_t ws_size,
                              hipStream_t stream) {
  const float* drug    = (const float*)d_in[0];
  const int*   ei      = (const int*)d_in[1];
  const float* protein = (const float*)d_in[3];
  const float* g1W = (const float*)d_in[4];
  const float* g1b = (const float*)d_in[5];
  const float* g2W = (const float*)d_in[6];
  const float* g2b = (const float*)d_in[7];
  const float* oW  = (const float*)d_in[8];
  const float* ob  = (const float*)d_in[9];
  const float* c1W = (const float*)d_in[10];
  const float* c1b = (const float*)d_in[11];
  const float* c2W = (const float*)d_in[12];
  const float* c2b = (const float*)d_in[13];
  const float* c3W = (const float*)d_in[14];
  const float* c3b = (const float*)d_in[15];
  const float* caW1 = (const float*)d_in[16];
  const float* caW2 = (const float*)d_in[17];
  const float* samW = (const float*)d_in[18];
  const float* samb = (const float*)d_in[19];
  const float* l1W = (const float*)d_in[20];
  const float* l1b = (const float*)d_in[21];
  const float* l2W = (const float*)d_in[22];
  const float* l2b = (const float*)d_in[23];
  const float* l3W = (const float*)d_in[24];
  const float* l3b = (const float*)d_in[25];

  // ---- workspace map: peak ~111 MiB (< 112 MiB known-safe) ----
  char* ws = (char*)d_ws;
  float* dinv  = (float*)(ws);                        // [0, 0.5M)
  int*   degi  = (int*)(ws + (size_t)524288);         // [0.5M, 1M)
  int*   cur   = (int*)(ws + (size_t)1048576);        // [1M, 1.5M)
  int*   offs  = (int*)(ws + (size_t)1572864);        // [1.5M, 2M+4)
  int*   bsum  = (int*)(ws + (size_t)2621440);
  int*   bexcl = (int*)(ws + (size_t)2625536);
  int*   csr   = (int*)(ws + (size_t)3145728);        // [3M, 5M)
  unsigned short* gA = (unsigned short*)(ws + (size_t)5242880);   // [5M, 21M)
  unsigned short* gB = (unsigned short*)(ws + (size_t)22020096);  // [21M, 37M)
  float* pooled = (float*)(ws + (size_t)105906176);   // [101M, 103M)
  unsigned short* gout = (unsigned short*)(ws + (size_t)108003328);  // [103M, 109M)
  unsigned short* Wbv  = (unsigned short*)(ws + (size_t)114294784);  // [109M, +768K)
  float* Kc      = (float*)(ws + (size_t)115081216);  // 1792 B
  float* bconst  = (float*)(ws + (size_t)115083136);  // 128 B
  float* edgeK   = (float*)(ws + (size_t)115083264);  // 6144 B
  float* edgeB   = (float*)(ws + (size_t)115089408);  // 512 B
  float* partial = (float*)(ws + (size_t)115343360);  // 512 KiB
  float* outp = (float*)d_out;

  // ---- CSR build + precompute ----
  k_zeroi<<<2 * NN / 256, 256, 0, stream>>>(degi);
  k_hist<<<EE / 256, 256, 0, stream>>>(ei, degi);
  k_dinv<<<NN / 256, 256, 0, stream>>>(degi, dinv);
  k_scan1<<<NN / 256, 256, 0, stream>>>(degi, offs, bsum);
  k_scan2<<<1, 512, 0, stream>>>(bsum, bexcl);
  k_scan3<<<NN / 256, 256, 0, stream>>>(offs, degi, bexcl, offs);
  k_scatter<<<EE / 256, 256, 0, stream>>>(ei, offs, cur, csr);
  k_prepwv<<<(12288 * 32) / 256, 256, 0, stream>>>(l1W, Wbv);
  k_prepk7<<<1, 512, 0, stream>>>(c1W, c1b, c2W, c2b, c3W, c3b, Kc, bconst);
  k_prepedge<<<26, 64, 0, stream>>>(c1W, c1b, c2W, c2b, c3W, c3b, edgeK, edgeB);

  // ---- GCN ----
  k_mm1<<<NN / 4, 256, 0, stream>>>(drug, g1W, dinv, gA);
  k_layer<true><<<NN / 4, 256, 0, stream>>>(gA, offs, csr, dinv, g1b, g2W, gB);
  k_layer<true><<<NN / 4, 256, 0, stream>>>(gB, offs, csr, dinv, g2b, g2W, gA);
  k_lastpool<<<BB, 512, 0, stream>>>(gA, offs, csr, dinv, g2b, pooled);

  // ---- output linear ----
  k_outmm<<<BB / 8, 256, 0, stream>>>(pooled, oW, ob, gout);

  // ---- fused CNN chain + CBAM + maxpool + MLP layer-1 ----
  k_cnn<<<BB, 512, 0, stream>>>(gout, protein, Kc, bconst, edgeK, edgeB,
                                caW1, caW2, samW, samb, Wbv, partial);

  // ---- MLP tail ----
  k_mlp2<<<BB / 16, 512, 0, stream>>>(partial, l1b, l2W, l2b, l3W, l3b, outp);
}

// Round 11
// 743.438 us; speedup vs baseline: 1.1162x; 1.1162x over previous
//
#include <hip/hip_runtime.h>
#include <cstdint>
#include <cstddef>

#define NN 131072
#define EE 524288
#define BB 4096
#define LL 768

typedef __attribute__((ext_vector_type(8))) short bf16x8;
typedef __attribute__((ext_vector_type(4))) float f32x4;
typedef __attribute__((ext_vector_type(2))) unsigned int uint2v;
typedef __attribute__((ext_vector_type(4))) unsigned int uint4v;

// ---------- helpers ----------
__device__ __forceinline__ float b2f(unsigned short u) {
  return __uint_as_float(((unsigned int)u) << 16);
}
__device__ __forceinline__ unsigned short f2b(float f) {
  unsigned int x = __float_as_uint(f);
  x += 0x7fff + ((x >> 16) & 1);  // RNE
  return (unsigned short)(x >> 16);
}
__device__ __forceinline__ unsigned f2b2(float lo, float hi) {
#if __has_builtin(__builtin_amdgcn_cvt_pk_bf16_f32)
  typedef __attribute__((ext_vector_type(2))) __bf16 bf16v2;
  bf16v2 r = __builtin_amdgcn_cvt_pk_bf16_f32(lo, hi);
  return __builtin_bit_cast(unsigned, r);
#else
  return (unsigned)f2b(lo) | ((unsigned)f2b(hi) << 16);
#endif
}
__device__ __forceinline__ float sigm(float x) { return 1.f / (1.f + expf(-x)); }
__device__ __forceinline__ float softplus_(float x) {
  return fmaxf(x, 0.f) + log1pf(expf(-fabsf(x)));
}

// ---------- CSR build ----------
__global__ __launch_bounds__(256) void k_zeroi(int* __restrict__ p) {
  p[blockIdx.x * 256 + threadIdx.x] = 0;
}
__global__ __launch_bounds__(256) void k_hist(const int* __restrict__ ei,
                                              int* __restrict__ degi) {
  int e = blockIdx.x * 256 + threadIdx.x;
  atomicAdd(&degi[ei[EE + e]], 1);
}
__global__ __launch_bounds__(256) void k_dinv(const int* __restrict__ degi,
                                              float* __restrict__ d) {
  int i = blockIdx.x * 256 + threadIdx.x;
  d[i] = rsqrtf((float)degi[i] + 1.0f);
}
__global__ __launch_bounds__(256) void k_scan1(const int* __restrict__ degi,
                                               int* __restrict__ incl,
                                               int* __restrict__ bsum) {
  __shared__ int s[256];
  int t = threadIdx.x;
  int i = blockIdx.x * 256 + t;
  s[t] = degi[i];
  __syncthreads();
  for (int off = 1; off < 256; off <<= 1) {
    int u = (t >= off) ? s[t - off] : 0;
    __syncthreads();
    s[t] += u;
    __syncthreads();
  }
  incl[i] = s[t];
  if (t == 255) bsum[blockIdx.x] = s[t];
}
__global__ __launch_bounds__(512) void k_scan2(const int* __restrict__ bsum,
                                               int* __restrict__ bexcl) {
  __shared__ int s[512];
  int t = threadIdx.x;
  s[t] = bsum[t];
  __syncthreads();
  int orig = s[t];
  for (int off = 1; off < 512; off <<= 1) {
    int u = (t >= off) ? s[t - off] : 0;
    __syncthreads();
    s[t] += u;
    __syncthreads();
  }
  bexcl[t] = s[t] - orig;
}
__global__ __launch_bounds__(256) void k_scan3(const int* __restrict__ incl,
                                               const int* __restrict__ degi,
                                               const int* __restrict__ bexcl,
                                               int* __restrict__ offs) {
  int t = threadIdx.x;
  int i = blockIdx.x * 256 + t;
  offs[i] = incl[i] - degi[i] + bexcl[blockIdx.x];
  if (i == 0) offs[NN] = EE;
}
__global__ __launch_bounds__(256) void k_scatter(const int* __restrict__ ei,
                                                 const int* __restrict__ offs,
                                                 int* __restrict__ cur,
                                                 int* __restrict__ csr) {
  int e = blockIdx.x * 256 + threadIdx.x;
  int dst = ei[EE + e];
  int pos = atomicAdd(&cur[dst], 1);
  csr[offs[dst] + pos] = ei[e];
}

// ---------- GCN (bf16 feature buffers) ----------
__global__ __launch_bounds__(256) void k_mm1(const float* __restrict__ drug,
                                             const float* __restrict__ W,
                                             const float* __restrict__ dinv,
                                             unsigned short* __restrict__ g) {
  __shared__ float Ws[9 * 64];
  int t = threadIdx.x;
  for (int i = t; i < 576; i += 256) Ws[i] = W[i];
  __syncthreads();
  int node = blockIdx.x * 4 + (t >> 6);
  int f = t & 63;
  const float* dr = drug + (size_t)node * 9;
  float s = 0.f;
#pragma unroll
  for (int k = 0; k < 9; k++) s += dr[k] * Ws[k * 64 + f];
  g[(size_t)node * 64 + f] = f2b(dinv[node] * s);
}

template <bool TANH>
__global__ __launch_bounds__(256) void k_layer(const unsigned short* __restrict__ gin,
                                               const int* __restrict__ offs,
                                               const int* __restrict__ csr,
                                               const float* __restrict__ dinv,
                                               const float* __restrict__ bias,
                                               const float* __restrict__ W,
                                               unsigned short* __restrict__ outb) {
  __shared__ float Ws[64 * 64];
  __shared__ float xs[4][64];
  const int t = threadIdx.x;
  for (int i = t; i < 4096; i += 256) Ws[i] = W[i];
  const int d = blockIdx.x * 4 + (t >> 6);
  const int f = t & 63;
  const float di = dinv[d];
  const int j0 = offs[d], j1 = offs[d + 1];
  float acc = b2f(gin[(size_t)d * 64 + f]);
  int j = j0;
  for (; j + 4 <= j1; j += 4) {
    int s0 = csr[j], s1 = csr[j + 1], s2 = csr[j + 2], s3 = csr[j + 3];
    float v0 = b2f(gin[(size_t)s0 * 64 + f]);
    float v1 = b2f(gin[(size_t)s1 * 64 + f]);
    float v2 = b2f(gin[(size_t)s2 * 64 + f]);
    float v3 = b2f(gin[(size_t)s3 * 64 + f]);
    acc += (v0 + v1) + (v2 + v3);
  }
  for (; j < j1; j++) acc += b2f(gin[(size_t)csr[j] * 64 + f]);
  float v = di * acc + bias[f];
  if (TANH) v = tanhf(v);
  xs[t >> 6][f] = v;
  __syncthreads();
  const float* xr = xs[t >> 6];
  float s = 0.f;
#pragma unroll
  for (int k = 0; k < 64; k++) s += xr[k] * Ws[k * 64 + f];
  outb[(size_t)d * 64 + f] = f2b(di * s);
}

__global__ __launch_bounds__(512) void k_lastpool(const unsigned short* __restrict__ gin,
                                                  const int* __restrict__ offs,
                                                  const int* __restrict__ csr,
                                                  const float* __restrict__ dinv,
                                                  const float* __restrict__ bias,
                                                  float* __restrict__ pooled) {
  __shared__ float smax[8][64], ssum[8][64];
  const int t = threadIdx.x;
  const int f = t & 63, grp = t >> 6;
  const int g = blockIdx.x;
  const float bf = bias[f];
  float mx = -1e30f, sm = 0.f;
#pragma unroll
  for (int i = 0; i < 4; i++) {
    int d = g * 32 + grp * 4 + i;
    const float di = dinv[d];
    const int j0 = offs[d], j1 = offs[d + 1];
    float acc = b2f(gin[(size_t)d * 64 + f]);
    int j = j0;
    for (; j + 4 <= j1; j += 4) {
      int s0 = csr[j], s1 = csr[j + 1], s2 = csr[j + 2], s3 = csr[j + 3];
      acc += (b2f(gin[(size_t)s0 * 64 + f]) + b2f(gin[(size_t)s1 * 64 + f]))
           + (b2f(gin[(size_t)s2 * 64 + f]) + b2f(gin[(size_t)s3 * 64 + f]));
    }
    for (; j < j1; j++) acc += b2f(gin[(size_t)csr[j] * 64 + f]);
    float v = di * acc + bf;
    mx = fmaxf(mx, v);
    sm += v;
  }
  smax[grp][f] = mx;
  ssum[grp][f] = sm;
  __syncthreads();
  if (t < 64) {
    float m = smax[0][t], s = ssum[0][t];
#pragma unroll
    for (int w = 1; w < 8; w++) { m = fmaxf(m, smax[w][t]); s += ssum[w][t]; }
    pooled[(size_t)g * 128 + t] = m;
    pooled[(size_t)g * 128 + 64 + t] = s * (1.f / 32.f);
  }
}

// gout(bf16): 8 graphs/block, 512 blocks (2/CU)
__global__ __launch_bounds__(256) void k_outmm(const float* __restrict__ pooled,
                                               const float* __restrict__ W,
                                               const float* __restrict__ bias,
                                               unsigned short* __restrict__ gout) {
  __shared__ float ps[8][128];
  int t = threadIdx.x;
  int g0 = blockIdx.x * 8;
  for (int i = t; i < 8 * 128; i += 256) ps[i >> 7][i & 127] = pooled[(size_t)g0 * 128 + i];
  __syncthreads();
  float a0[8], a1[8], a2[8];
#pragma unroll
  for (int j = 0; j < 8; j++) { a0[j] = 0.f; a1[j] = 0.f; a2[j] = 0.f; }
  for (int k = 0; k < 128; k++) {
    float w0 = W[k * 768 + t];
    float w1 = W[k * 768 + t + 256];
    float w2 = W[k * 768 + t + 512];
#pragma unroll
    for (int j = 0; j < 8; j++) {
      float p = ps[j][k];
      a0[j] += p * w0; a1[j] += p * w1; a2[j] += p * w2;
    }
  }
  float b0 = bias[t], b1 = bias[t + 256], b2 = bias[t + 512];
  for (int j = 0; j < 8; j++) {
    gout[(size_t)(g0 + j) * 768 + t]       = f2b(a0[j] + b0);
    gout[(size_t)(g0 + j) * 768 + t + 256] = f2b(a1[j] + b1);
    gout[(size_t)(g0 + j) * 768 + t + 512] = f2b(a2[j] + b2);
  }
}

// ---------- composite conv precompute ----------
__global__ __launch_bounds__(512) void k_prepk7(
    const float* __restrict__ W1, const float* __restrict__ b1,
    const float* __restrict__ W2, const float* __restrict__ b2,
    const float* __restrict__ W3, const float* __restrict__ b3,
    float* __restrict__ Kc, float* __restrict__ bconst) {
  __shared__ float W1s[192], W2s[3072], W3s[3072];
  __shared__ float b1s[32], b2s[32], b3s[32];
  __shared__ float M[320];
  __shared__ float beta[32];
  const int t = threadIdx.x;
  for (int i = t; i < 3072; i += 512) { W2s[i] = W2[i]; W3s[i] = W3[i]; }
  if (t < 192) W1s[t] = W1[t];
  if (t >= 192 && t < 224) { int i = t - 192; b1s[i] = b1[i]; b2s[i] = b2[i]; b3s[i] = b3[i]; }
  __syncthreads();
  if (t < 320) {
    int i = t / 10, rem = t % 10, c = rem / 5, t12 = rem % 5;
    float s = 0.f;
    for (int j = 0; j < 32; j++)
#pragma unroll
      for (int t2 = 0; t2 < 3; t2++) {
        int t1 = t12 - t2;
        if (t1 >= 0 && t1 < 3) s += W2s[(i * 32 + j) * 3 + t2] * W1s[(j * 2 + c) * 3 + t1];
      }
    M[i * 10 + c * 5 + t12] = s;
  }
  if (t >= 384 && t < 416) {
    int i = t - 384;
    float s = b2s[i];
    for (int j = 0; j < 32; j++) {
      float w = W2s[(i * 32 + j) * 3] + W2s[(i * 32 + j) * 3 + 1] + W2s[(i * 32 + j) * 3 + 2];
      s += w * b1s[j];
    }
    beta[i] = s;
  }
  __syncthreads();
  if (t < 448) {
    int o = t / 14, rem = t % 14, c = rem / 7, tt = rem % 7;
    float s = 0.f;
    for (int i = 0; i < 32; i++)
#pragma unroll
      for (int t3 = 0; t3 < 3; t3++) {
        int t12 = tt - t3;
        if (t12 >= 0 && t12 < 5) s += W3s[(o * 32 + i) * 3 + t3] * M[i * 10 + c * 5 + t12];
      }
    Kc[o * 14 + c * 7 + tt] = s;
  }
  if (t >= 480 && t < 512) {
    int o = t - 480;
    float s = b3s[o];
    for (int i = 0; i < 32; i++) {
      float w = W3s[(o * 32 + i) * 3] + W3s[(o * 32 + i) * 3 + 1] + W3s[(o * 32 + i) * 3 + 2];
      s += w * beta[i];
    }
    bconst[o] = s;
  }
}

__global__ __launch_bounds__(64) void k_prepedge(
    const float* __restrict__ W1, const float* __restrict__ b1,
    const float* __restrict__ W2, const float* __restrict__ b2,
    const float* __restrict__ W3, const float* __restrict__ b3,
    float* __restrict__ edgeK, float* __restrict__ edgeB) {
  __shared__ float W1s[192], W2s[3072], W3s[3072];
  __shared__ float b1s[32], b2s[32], b3s[32];
  __shared__ float cl[2][6], h1[32][5], h2[32][4];
  const int t = threadIdx.x;
  const int side = blockIdx.x / 13, run = blockIdx.x % 13;
  for (int i = t; i < 3072; i += 64) { W2s[i] = W2[i]; W3s[i] = W3[i]; }
  for (int i = t; i < 192; i += 64) W1s[i] = W1[i];
  if (t < 32) { b1s[t] = b1[t]; b2s[t] = b2[t]; b3s[t] = b3[t]; }
  if (t < 12) cl[t / 6][t % 6] = (run == t) ? 1.f : 0.f;
  __syncthreads();
  const bool ub = (run == 12);
  if (t < 32) {
    int i = t;
    for (int p = 0; p < 5; p++) {
      float s = ub ? b1s[i] : 0.f;
      for (int c = 0; c < 2; c++)
#pragma unroll
        for (int tau = 0; tau < 3; tau++) {
          int x = (side == 0) ? (p + tau - 1) : (p + tau);
          if (x >= 0 && x < 6) s += W1s[(i * 2 + c) * 3 + tau] * cl[c][x];
        }
      h1[i][p] = s;
    }
  }
  __syncthreads();
  if (t < 32) {
    int o = t;
    for (int u = 0; u < 4; u++) {
      float s = ub ? b2s[o] : 0.f;
      for (int i = 0; i < 32; i++)
#pragma unroll
        for (int tau = 0; tau < 3; tau++) {
          int q = (side == 0) ? (u + tau - 1) : (u + tau);
          if (q >= 0 && q < 5) s += W2s[(o * 32 + i) * 3 + tau] * h1[i][q];
        }
      h2[o][u] = s;
    }
  }
  __syncthreads();
  if (t < 32) {
    int o = t;
    for (int e = 0; e < 2; e++) {
      float s = ub ? b3s[o] : 0.f;
      for (int i = 0; i < 32; i++)
#pragma unroll
        for (int tau = 0; tau < 3; tau++) {
          int u = (side == 0) ? (e + tau - 1) : (e + tau + 1);
          if (u >= 0 && u < 4) s += W3s[(o * 32 + i) * 3 + tau] * h2[i][u];
        }
      int slot = (side * 2 + e) * 32 + o;
      if (ub) edgeB[slot] = s;
      else edgeK[slot * 12 + run] = s;
    }
  }
}

// Wb in MFMA B-fragment order, bf16: Wb[((kt*2+nt)*64+lane)*8+j] = W1[o][korig]
__global__ __launch_bounds__(256) void k_prepw(const float* __restrict__ W,
                                               unsigned short* __restrict__ Wb) {
  int idx = blockIdx.x * 256 + threadIdx.x;
  int j = idx & 7;
  int lane = (idx >> 3) & 63;
  int nt = (idx >> 9) & 1;
  int kt = idx >> 10;
  int o = nt * 16 + (lane & 15);
  int k = kt * 32 + (lane >> 4) * 8 + j;
  int korig = (k & 31) * 384 + (k >> 5);
  Wb[idx] = f2b(W[(size_t)o * 12288 + korig]);
}

// ---------- fused CNN chain: composite conv + CBAM + pool; coalesced pvec ----------
__global__ __launch_bounds__(512) void k_cnn(
    const unsigned short* __restrict__ gout, const float* __restrict__ protein,
    const float* __restrict__ Kc, const float* __restrict__ bconst,
    const float* __restrict__ edgeK, const float* __restrict__ edgeB,
    const float* __restrict__ caW1, const float* __restrict__ caW2,
    const float* __restrict__ samW, const float* __restrict__ samb,
    unsigned short* __restrict__ pvec) {
  __shared__ float combf[2][776];
  __shared__ float K7s[448];
  __shared__ float bcs[32];
  __shared__ float xbuf[2320];       // xm@0, xM@772, att@1544
  __shared__ alignas(16) unsigned short pv[12288];  // staged pooled vector (bf16)
  __shared__ float wmaxs[8][32], wsums[8][32];
  __shared__ float cmaxs[32], csums[32], t1buf[2][16], feats[32], samWs[8];
  const int t = threadIdx.x;
  const int b = blockIdx.x;
  const int lane = t & 63, wv = t >> 6, lx = lane & 15, quad = lane >> 4;

  // S0: stage
  for (int i = t; i < 1552; i += 512) {
    int c = i / 776, li = i - c * 776;
    int l = li - 4;
    float v = 0.f;
    if (l >= 0 && l < LL)
      v = c ? protein[(size_t)b * LL + l] : b2f(gout[(size_t)b * LL + l]);
    combf[c][li] = v;
  }
  if (t < 448) K7s[t] = Kc[t];
  if (t >= 448 && t < 480) bcs[t - 448] = bconst[t - 448];
  if (t >= 480 && t < 486) samWs[t - 480] = samW[t - 480];
  if (t == 486) samWs[6] = samb[0];
  __syncthreads();

  // S1: composite 7-tap conv -> a3[n][mt] registers
  f32x4 a3[6][2];
#pragma unroll
  for (int mt = 0; mt < 2; mt++) {
    float kr[4][14];
#pragma unroll
    for (int r = 0; r < 4; r++) {
      int o = mt * 16 + quad * 4 + r;
#pragma unroll
      for (int q = 0; q < 14; q++) kr[r][q] = K7s[o * 14 + q];
    }
#pragma unroll
    for (int n = 0; n < 6; n++) {
      int l = (wv * 6 + n) * 16 + lx;
      float w0[7], w1[7];
#pragma unroll
      for (int q = 0; q < 7; q++) { w0[q] = combf[0][l + 1 + q]; w1[q] = combf[1][l + 1 + q]; }
#pragma unroll
      for (int r = 0; r < 4; r++) {
        float s = bcs[mt * 16 + quad * 4 + r];
#pragma unroll
        for (int q = 0; q < 7; q++) s += kr[r][q] * w0[q] + kr[r][7 + q] * w1[q];
        a3[n][mt][r] = s;
      }
    }
  }
  // edge fixup: l in {0,1} and {766,767}
  {
    bool left = (wv == 0 && lx < 2);
    bool right = (wv == 7 && lx >= 14);
    if (left || right) {
      int n = left ? 0 : 5;
      int e = left ? lx : (lx - 14);
      int side = left ? 0 : 1;
      int cbase = left ? 4 : 766;
#pragma unroll
      for (int mt = 0; mt < 2; mt++)
#pragma unroll
        for (int r = 0; r < 4; r++) {
          int o = mt * 16 + quad * 4 + r;
          int slot = (side * 2 + e) * 32 + o;
          float s = edgeB[slot];
          const float* ek = &edgeK[slot * 12];
#pragma unroll
          for (int w = 0; w < 6; w++)
            s += ek[w] * combf[0][cbase + w] + ek[6 + w] * combf[1][cbase + w];
          a3[n][mt][r] = s;
        }
    }
  }

  // S3: channel stats
  float tmax[2][4], tsum[2][4];
#pragma unroll
  for (int mt = 0; mt < 2; mt++)
#pragma unroll
    for (int r = 0; r < 4; r++) { tmax[mt][r] = -1e30f; tsum[mt][r] = 0.f; }
#pragma unroll
  for (int n = 0; n < 6; n++)
#pragma unroll
    for (int mt = 0; mt < 2; mt++)
#pragma unroll
      for (int r = 0; r < 4; r++) {
        float v = a3[n][mt][r];
        tmax[mt][r] = fmaxf(tmax[mt][r], v);
        tsum[mt][r] += v;
      }
#pragma unroll
  for (int mt = 0; mt < 2; mt++)
#pragma unroll
    for (int r = 0; r < 4; r++) {
      float m = tmax[mt][r], s = tsum[mt][r];
      for (int d = 1; d < 16; d <<= 1) {
        m = fmaxf(m, __shfl_xor(m, d));
        s += __shfl_xor(s, d);
      }
      if (lx == 0) {
        wmaxs[wv][mt * 16 + quad * 4 + r] = m;
        wsums[wv][mt * 16 + quad * 4 + r] = s;
      }
    }
  __syncthreads();

  // S4: cross-wave stats + channel-attention MLP
  if (t < 32) {
    float m = wmaxs[0][t], s = wsums[0][t];
#pragma unroll
    for (int w = 1; w < 8; w++) { m = fmaxf(m, wmaxs[w][t]); s += wsums[w][t]; }
    cmaxs[t] = m;
    csums[t] = s;
  }
  __syncthreads();
  if (t < 32) {
    int j = t & 15;
    int mean = t >> 4;
    float s = 0.f;
    for (int o = 0; o < 32; o++) {
      float v = mean ? csums[o] * (1.f / 768.f) : cmaxs[o];
      s += v * caW1[j * 32 + o];
    }
    t1buf[mean][j] = s;
  }
  __syncthreads();
  if (t < 32) {
    float m1 = 0.f, m2 = 0.f;
    for (int j = 0; j < 16; j++) {
      m1 += t1buf[0][j] * caW2[t * 16 + j];
      m2 += t1buf[1][j] * caW2[t * 16 + j];
    }
    feats[t] = sigm(fmaxf(m1, 0.f) + fmaxf(m2, 0.f));
  }
  __syncthreads();

  // S5: spatial stats from registers
  float frq[2][4];
#pragma unroll
  for (int mt = 0; mt < 2; mt++)
#pragma unroll
    for (int r = 0; r < 4; r++) frq[mt][r] = feats[mt * 16 + quad * 4 + r];
#pragma unroll
  for (int n = 0; n < 6; n++) {
    int l = (wv * 6 + n) * 16 + lx;
    float sm = 0.f, mx = -1e30f;
#pragma unroll
    for (int mt = 0; mt < 2; mt++)
#pragma unroll
      for (int r = 0; r < 4; r++) {
        float v = a3[n][mt][r] * frq[mt][r];
        sm += v;
        mx = fmaxf(mx, v);
      }
    sm += __shfl_xor(sm, 16); mx = fmaxf(mx, __shfl_xor(mx, 16));
    sm += __shfl_xor(sm, 32); mx = fmaxf(mx, __shfl_xor(mx, 32));
    if (quad == 0) {
      xbuf[l] = sm * (1.f / 32.f);
      xbuf[772 + l] = mx;
    }
  }
  __syncthreads();

  // S6: spatial attention conv + sigmoid
  for (int l = t; l < LL; l += 512) {
    float a = samWs[6];
#pragma unroll
    for (int k = 0; k < 3; k++) {
      int ll = l + k - 1;
      float vm = (ll >= 0 && ll < LL) ? xbuf[ll] : 0.f;
      float vM = (ll >= 0 && ll < LL) ? xbuf[772 + ll] : 0.f;
      a += samWs[k] * vm + samWs[3 + k] * vM;
    }
    xbuf[1544 + l] = sigm(a);
  }
  __syncthreads();

  // S7: scale + maxpool2 via lane-pair shuffle -> pv (LDS), then coalesced store
#pragma unroll
  for (int n = 0; n < 6; n++) {
    int l = (wv * 6 + n) * 16 + lx;
    float at = xbuf[1544 + l];
    float m[2][4];
#pragma unroll
    for (int mt = 0; mt < 2; mt++)
#pragma unroll
      for (int r = 0; r < 4; r++) {
        float v = a3[n][mt][r] * frq[mt][r] * at;
        m[mt][r] = fmaxf(v, __shfl_xor(v, 1));
      }
    if (!(lx & 1)) {
      int lp = l >> 1;
#pragma unroll
      for (int mt = 0; mt < 2; mt++) {
        uint2v pk;
        pk.x = f2b2(m[mt][0], m[mt][1]);
        pk.y = f2b2(m[mt][2], m[mt][3]);
        *(uint2v*)&pv[lp * 32 + mt * 16 + quad * 4] = pk;
      }
    }
  }
  __syncthreads();
  // coalesced write-out: 1536 uint4 (24 KB), 1 KB per wave-instruction
  {
    uint4v* dst = (uint4v*)(pvec + (size_t)b * 12288);
    const uint4v* src = (const uint4v*)pv;
#pragma unroll
    for (int p = 0; p < 3; p++) {
      int idx = t + p * 512;
      dst[idx] = src[idx];
    }
  }
}

// MLP layer-1 partials (MFMA): block = (16 graphs, 1/4 of K); 1024 blocks.
__global__ __launch_bounds__(512) void k_mlp1(
    const unsigned short* __restrict__ pvec, const unsigned short* __restrict__ Wb,
    float* __restrict__ partial) {
  __shared__ float part[8][16][32];
  const int t = threadIdx.x;
  const int lane = t & 63, wv = t >> 6, lx = lane & 15, quad = lane >> 4;
  const int g0 = (blockIdx.x >> 2) * 16;
  const int kc = blockIdx.x & 3;
  const unsigned short* arow = pvec + (size_t)(g0 + lx) * 12288 + quad * 8;

  f32x4 acc0 = {0.f, 0.f, 0.f, 0.f}, acc1 = {0.f, 0.f, 0.f, 0.f};
  const int kt0 = kc * 96 + wv * 12;
#pragma unroll 4
  for (int i = 0; i < 12; i++) {
    const int kt = kt0 + i;
    bf16x8 A = *(const bf16x8*)&arow[kt * 32];
    bf16x8 B0 = *(const bf16x8*)&Wb[((kt * 2 + 0) * 64 + lane) * 8];
    bf16x8 B1 = *(const bf16x8*)&Wb[((kt * 2 + 1) * 64 + lane) * 8];
    acc0 = __builtin_amdgcn_mfma_f32_16x16x32_bf16(A, B0, acc0, 0, 0, 0);
    acc1 = __builtin_amdgcn_mfma_f32_16x16x32_bf16(A, B1, acc1, 0, 0, 0);
  }
#pragma unroll
  for (int r = 0; r < 4; r++) {
    part[wv][quad * 4 + r][lx] = acc0[r];
    part[wv][quad * 4 + r][16 + lx] = acc1[r];
  }
  __syncthreads();
  {
    int g = t >> 5, o = t & 31;
    float s = 0.f;
#pragma unroll
    for (int w = 0; w < 8; w++) s += part[w][g][o];
    partial[((size_t)kc * BB + g0 + g) * 32 + o] = s;
  }
}

// MLP tail: reduce 4 K-chunk partials + softplus chain + layers 2,3.
__global__ __launch_bounds__(512) void k_mlp2(
    const float* __restrict__ partial,
    const float* __restrict__ lb1, const float* __restrict__ W2,
    const float* __restrict__ lb2, const float* __restrict__ W3,
    const float* __restrict__ lb3, float* __restrict__ out) {
  __shared__ float s1[16][32];
  __shared__ float s2[16][32];
  const int t = threadIdx.x;
  const int g0 = blockIdx.x * 16;
  {
    int g = t >> 5, o = t & 31;
    float s = lb1[o];
#pragma unroll
    for (int kc = 0; kc < 4; kc++) s += partial[((size_t)kc * BB + g0 + g) * 32 + o];
    s1[g][o] = softplus_(s);
  }
  __syncthreads();
  {
    int g = t >> 5, o = t & 31;
    float s = lb2[o];
    for (int kk = 0; kk < 32; kk++) s += s1[g][kk] * W2[o * 32 + kk];
    s2[g][o] = softplus_(s);
  }
  __syncthreads();
  if (t < 16) {
    float s = lb3[0];
    for (int kk = 0; kk < 32; kk++) s += s2[t][kk] * W3[kk];
    out[g0 + t] = softplus_(s);
  }
}

extern "C" void kernel_launch(void* const* d_in, const int* in_sizes, int n_in,
                              void* d_out, int out_size, void* d_ws, size_t ws_size,
                              hipStream_t stream) {
  const float* drug    = (const float*)d_in[0];
  const int*   ei      = (const int*)d_in[1];
  const float* protein = (const float*)d_in[3];
  const float* g1W = (const float*)d_in[4];
  const float* g1b = (const float*)d_in[5];
  const float* g2W = (const float*)d_in[6];
  const float* g2b = (const float*)d_in[7];
  const float* oW  = (const float*)d_in[8];
  const float* ob  = (const float*)d_in[9];
  const float* c1W = (const float*)d_in[10];
  const float* c1b = (const float*)d_in[11];
  const float* c2W = (const float*)d_in[12];
  const float* c2b = (const float*)d_in[13];
  const float* c3W = (const float*)d_in[14];
  const float* c3b = (const float*)d_in[15];
  const float* caW1 = (const float*)d_in[16];
  const float* caW2 = (const float*)d_in[17];
  const float* samW = (const float*)d_in[18];
  const float* samb = (const float*)d_in[19];
  const float* l1W = (const float*)d_in[20];
  const float* l1b = (const float*)d_in[21];
  const float* l2W = (const float*)d_in[22];
  const float* l2b = (const float*)d_in[23];
  const float* l3W = (const float*)d_in[24];
  const float* l3b = (const float*)d_in[25];

  // ---- workspace map: peak exactly 112 MiB (known-safe) ----
  char* ws = (char*)d_ws;
  float* dinv  = (float*)(ws);                        // [0, 0.5M)
  int*   degi  = (int*)(ws + (size_t)524288);         // [0.5M, 1M)
  int*   cur   = (int*)(ws + (size_t)1048576);        // [1M, 1.5M)
  int*   offs  = (int*)(ws + (size_t)1572864);        // [1.5M, 2M+4)
  int*   bsum  = (int*)(ws + (size_t)2621440);
  int*   bexcl = (int*)(ws + (size_t)2625536);
  int*   csr   = (int*)(ws + (size_t)3145728);        // [3M, 5M)
  unsigned short* gA = (unsigned short*)(ws + (size_t)5242880);   // [5M, 21M)
  unsigned short* gB = (unsigned short*)(ws + (size_t)22020096);  // [21M, 37M)
  unsigned short* pvec = (unsigned short*)(ws + (size_t)5242880); // overlays gA/gB
  float* pooled = (float*)(ws + (size_t)105906176);   // [101M, 103M)
  unsigned short* gout = (unsigned short*)(ws + (size_t)108003328);  // [103M, 109M)
  unsigned short* Wb   = (unsigned short*)(ws + (size_t)114294784);  // 768K
  float* Kc      = (float*)(ws + (size_t)115081216);  // 1792 B
  float* bconst  = (float*)(ws + (size_t)115083136);  // 128 B
  float* edgeK   = (float*)(ws + (size_t)115083264);  // 6144 B
  float* edgeB   = (float*)(ws + (size_t)115089408);  // 512 B
  float* partial = (float*)(ws + (size_t)115343360);  // 2 MiB, ends at 112 MiB
  float* outp = (float*)d_out;

  // ---- CSR build + precompute ----
  k_zeroi<<<2 * NN / 256, 256, 0, stream>>>(degi);
  k_hist<<<EE / 256, 256, 0, stream>>>(ei, degi);
  k_dinv<<<NN / 256, 256, 0, stream>>>(degi, dinv);
  k_scan1<<<NN / 256, 256, 0, stream>>>(degi, offs, bsum);
  k_scan2<<<1, 512, 0, stream>>>(bsum, bexcl);
  k_scan3<<<NN / 256, 256, 0, stream>>>(offs, degi, bexcl, offs);
  k_scatter<<<EE / 256, 256, 0, stream>>>(ei, offs, cur, csr);
  k_prepw<<<(12288 * 32) / 256, 256, 0, stream>>>(l1W, Wb);
  k_prepk7<<<1, 512, 0, stream>>>(c1W, c1b, c2W, c2b, c3W, c3b, Kc, bconst);
  k_prepedge<<<26, 64, 0, stream>>>(c1W, c1b, c2W, c2b, c3W, c3b, edgeK, edgeB);

  // ---- GCN ----
  k_mm1<<<NN / 4, 256, 0, stream>>>(drug, g1W, dinv, gA);
  k_layer<true><<<NN / 4, 256, 0, stream>>>(gA, offs, csr, dinv, g1b, g2W, gB);
  k_layer<true><<<NN / 4, 256, 0, stream>>>(gB, offs, csr, dinv, g2b, g2W, gA);
  k_lastpool<<<BB, 512, 0, stream>>>(gA, offs, csr, dinv, g2b, pooled);

  // ---- output linear ----
  k_outmm<<<BB / 8, 256, 0, stream>>>(pooled, oW, ob, gout);

  // ---- fused CNN chain (composite conv) + CBAM + maxpool ----
  k_cnn<<<BB, 512, 0, stream>>>(gout, protein, Kc, bconst, edgeK, edgeB,
                                caW1, caW2, samW, samb, pvec);

  // ---- MLP head (MFMA, K-split 4x) ----
  k_mlp1<<<(BB / 16) * 4, 512, 0, stream>>>(pvec, Wb, partial);
  k_mlp2<<<BB / 16, 512, 0, stream>>>(partial, l1b, l2W, l2b, l3W, l3b, outp);
}

// Round 12
// 698.814 us; speedup vs baseline: 1.1875x; 1.0639x over previous
//
#include <hip/hip_runtime.h>
#include <cstdint>
#include <cstddef>

#define NN 131072
#define EE 524288
#define BB 4096
#define LL 768

typedef __attribute__((ext_vector_type(8))) short bf16x8;
typedef __attribute__((ext_vector_type(4))) float f32x4;
typedef __attribute__((ext_vector_type(2))) unsigned int uint2v;

// ---------- helpers ----------
__device__ __forceinline__ float b2f(unsigned short u) {
  return __uint_as_float(((unsigned int)u) << 16);
}
__device__ __forceinline__ unsigned short f2b(float f) {
  unsigned int x = __float_as_uint(f);
  x += 0x7fff + ((x >> 16) & 1);  // RNE
  return (unsigned short)(x >> 16);
}
__device__ __forceinline__ unsigned f2b2(float lo, float hi) {
#if __has_builtin(__builtin_amdgcn_cvt_pk_bf16_f32)
  typedef __attribute__((ext_vector_type(2))) __bf16 bf16v2;
  bf16v2 r = __builtin_amdgcn_cvt_pk_bf16_f32(lo, hi);
  return __builtin_bit_cast(unsigned, r);
#else
  return (unsigned)f2b(lo) | ((unsigned)f2b(hi) << 16);
#endif
}
__device__ __forceinline__ float sigm(float x) { return 1.f / (1.f + expf(-x)); }
__device__ __forceinline__ float softplus_(float x) {
  return fmaxf(x, 0.f) + log1pf(expf(-fabsf(x)));
}

// ---------- CSR build ----------
__global__ __launch_bounds__(256) void k_zeroi(int* __restrict__ p) {
  p[blockIdx.x * 256 + threadIdx.x] = 0;
}
__global__ __launch_bounds__(256) void k_hist(const int* __restrict__ ei,
                                              int* __restrict__ degi) {
  int e = blockIdx.x * 256 + threadIdx.x;
  atomicAdd(&degi[ei[EE + e]], 1);
}
__global__ __launch_bounds__(256) void k_dinv(const int* __restrict__ degi,
                                              float* __restrict__ d) {
  int i = blockIdx.x * 256 + threadIdx.x;
  d[i] = rsqrtf((float)degi[i] + 1.0f);
}
__global__ __launch_bounds__(256) void k_scan1(const int* __restrict__ degi,
                                               int* __restrict__ incl,
                                               int* __restrict__ bsum) {
  __shared__ int s[256];
  int t = threadIdx.x;
  int i = blockIdx.x * 256 + t;
  s[t] = degi[i];
  __syncthreads();
  for (int off = 1; off < 256; off <<= 1) {
    int u = (t >= off) ? s[t - off] : 0;
    __syncthreads();
    s[t] += u;
    __syncthreads();
  }
  incl[i] = s[t];
  if (t == 255) bsum[blockIdx.x] = s[t];
}
__global__ __launch_bounds__(512) void k_scan2(const int* __restrict__ bsum,
                                               int* __restrict__ bexcl) {
  __shared__ int s[512];
  int t = threadIdx.x;
  s[t] = bsum[t];
  __syncthreads();
  int orig = s[t];
  for (int off = 1; off < 512; off <<= 1) {
    int u = (t >= off) ? s[t - off] : 0;
    __syncthreads();
    s[t] += u;
    __syncthreads();
  }
  bexcl[t] = s[t] - orig;
}
__global__ __launch_bounds__(256) void k_scan3(const int* __restrict__ incl,
                                               const int* __restrict__ degi,
                                               const int* __restrict__ bexcl,
                                               int* __restrict__ offs) {
  int t = threadIdx.x;
  int i = blockIdx.x * 256 + t;
  offs[i] = incl[i] - degi[i] + bexcl[blockIdx.x];
  if (i == 0) offs[NN] = EE;
}
__global__ __launch_bounds__(256) void k_scatter(const int* __restrict__ ei,
                                                 const int* __restrict__ offs,
                                                 int* __restrict__ cur,
                                                 int* __restrict__ csr) {
  int e = blockIdx.x * 256 + threadIdx.x;
  int dst = ei[EE + e];
  int pos = atomicAdd(&cur[dst], 1);
  csr[offs[dst] + pos] = ei[e];
}

// ---------- GCN (bf16 feature buffers) ----------
__global__ __launch_bounds__(256) void k_mm1(const float* __restrict__ drug,
                                             const float* __restrict__ W,
                                             const float* __restrict__ dinv,
                                             unsigned short* __restrict__ g) {
  __shared__ float Ws[9 * 64];
  int t = threadIdx.x;
  for (int i = t; i < 576; i += 256) Ws[i] = W[i];
  __syncthreads();
  int node = blockIdx.x * 4 + (t >> 6);
  int f = t & 63;
  const float* dr = drug + (size_t)node * 9;
  float s = 0.f;
#pragma unroll
  for (int k = 0; k < 9; k++) s += dr[k] * Ws[k * 64 + f];
  g[(size_t)node * 64 + f] = f2b(dinv[node] * s);
}

template <bool TANH>
__global__ __launch_bounds__(256) void k_layer(const unsigned short* __restrict__ gin,
                                               const int* __restrict__ offs,
                                               const int* __restrict__ csr,
                                               const float* __restrict__ dinv,
                                               const float* __restrict__ bias,
                                               const float* __restrict__ W,
                                               unsigned short* __restrict__ outb) {
  __shared__ float Ws[64 * 64];
  __shared__ float xs[4][64];
  const int t = threadIdx.x;
  for (int i = t; i < 4096; i += 256) Ws[i] = W[i];
  const int d = blockIdx.x * 4 + (t >> 6);
  const int f = t & 63;
  const float di = dinv[d];
  const int j0 = offs[d], j1 = offs[d + 1];
  float acc = b2f(gin[(size_t)d * 64 + f]);
  int j = j0;
  for (; j + 4 <= j1; j += 4) {
    int s0 = csr[j], s1 = csr[j + 1], s2 = csr[j + 2], s3 = csr[j + 3];
    float v0 = b2f(gin[(size_t)s0 * 64 + f]);
    float v1 = b2f(gin[(size_t)s1 * 64 + f]);
    float v2 = b2f(gin[(size_t)s2 * 64 + f]);
    float v3 = b2f(gin[(size_t)s3 * 64 + f]);
    acc += (v0 + v1) + (v2 + v3);
  }
  for (; j < j1; j++) acc += b2f(gin[(size_t)csr[j] * 64 + f]);
  float v = di * acc + bias[f];
  if (TANH) v = tanhf(v);
  xs[t >> 6][f] = v;
  __syncthreads();
  const float* xr = xs[t >> 6];
  float s = 0.f;
#pragma unroll
  for (int k = 0; k < 64; k++) s += xr[k] * Ws[k * 64 + f];
  outb[(size_t)d * 64 + f] = f2b(di * s);
}

__global__ __launch_bounds__(512) void k_lastpool(const unsigned short* __restrict__ gin,
                                                  const int* __restrict__ offs,
                                                  const int* __restrict__ csr,
                                                  const float* __restrict__ dinv,
                                                  const float* __restrict__ bias,
                                                  float* __restrict__ pooled) {
  __shared__ float smax[8][64], ssum[8][64];
  const int t = threadIdx.x;
  const int f = t & 63, grp = t >> 6;
  const int g = blockIdx.x;
  const float bf = bias[f];
  float mx = -1e30f, sm = 0.f;
#pragma unroll
  for (int i = 0; i < 4; i++) {
    int d = g * 32 + grp * 4 + i;
    const float di = dinv[d];
    const int j0 = offs[d], j1 = offs[d + 1];
    float acc = b2f(gin[(size_t)d * 64 + f]);
    int j = j0;
    for (; j + 4 <= j1; j += 4) {
      int s0 = csr[j], s1 = csr[j + 1], s2 = csr[j + 2], s3 = csr[j + 3];
      acc += (b2f(gin[(size_t)s0 * 64 + f]) + b2f(gin[(size_t)s1 * 64 + f]))
           + (b2f(gin[(size_t)s2 * 64 + f]) + b2f(gin[(size_t)s3 * 64 + f]));
    }
    for (; j < j1; j++) acc += b2f(gin[(size_t)csr[j] * 64 + f]);
    float v = di * acc + bf;
    mx = fmaxf(mx, v);
    sm += v;
  }
  smax[grp][f] = mx;
  ssum[grp][f] = sm;
  __syncthreads();
  if (t < 64) {
    float m = smax[0][t], s = ssum[0][t];
#pragma unroll
    for (int w = 1; w < 8; w++) { m = fmaxf(m, smax[w][t]); s += ssum[w][t]; }
    pooled[(size_t)g * 128 + t] = m;
    pooled[(size_t)g * 128 + 64 + t] = s * (1.f / 32.f);
  }
}

// gout(bf16): 16 graphs/block (round-8 best config)
__global__ __launch_bounds__(256) void k_outmm(const float* __restrict__ pooled,
                                               const float* __restrict__ W,
                                               const float* __restrict__ bias,
                                               unsigned short* __restrict__ gout) {
  __shared__ float ps[16][128];
  int t = threadIdx.x;
  int g0 = blockIdx.x * 16;
  for (int i = t; i < 16 * 128; i += 256) ps[i >> 7][i & 127] = pooled[(size_t)g0 * 128 + i];
  __syncthreads();
  float a0[16], a1[16], a2[16];
#pragma unroll
  for (int j = 0; j < 16; j++) { a0[j] = 0.f; a1[j] = 0.f; a2[j] = 0.f; }
  for (int k = 0; k < 128; k++) {
    float w0 = W[k * 768 + t];
    float w1 = W[k * 768 + t + 256];
    float w2 = W[k * 768 + t + 512];
#pragma unroll
    for (int j = 0; j < 16; j++) {
      float p = ps[j][k];
      a0[j] += p * w0; a1[j] += p * w1; a2[j] += p * w2;
    }
  }
  float b0 = bias[t], b1 = bias[t + 256], b2 = bias[t + 512];
  for (int j = 0; j < 16; j++) {
    gout[(size_t)(g0 + j) * 768 + t]       = f2b(a0[j] + b0);
    gout[(size_t)(g0 + j) * 768 + t + 256] = f2b(a1[j] + b1);
    gout[(size_t)(g0 + j) * 768 + t + 512] = f2b(a2[j] + b2);
  }
}

// ---------- composite conv precompute ----------
__global__ __launch_bounds__(512) void k_prepk7(
    const float* __restrict__ W1, const float* __restrict__ b1,
    const float* __restrict__ W2, const float* __restrict__ b2,
    const float* __restrict__ W3, const float* __restrict__ b3,
    float* __restrict__ Kc, float* __restrict__ bconst) {
  __shared__ float W1s[192], W2s[3072], W3s[3072];
  __shared__ float b1s[32], b2s[32], b3s[32];
  __shared__ float M[320];
  __shared__ float beta[32];
  const int t = threadIdx.x;
  for (int i = t; i < 3072; i += 512) { W2s[i] = W2[i]; W3s[i] = W3[i]; }
  if (t < 192) W1s[t] = W1[t];
  if (t >= 192 && t < 224) { int i = t - 192; b1s[i] = b1[i]; b2s[i] = b2[i]; b3s[i] = b3[i]; }
  __syncthreads();
  if (t < 320) {
    int i = t / 10, rem = t % 10, c = rem / 5, t12 = rem % 5;
    float s = 0.f;
    for (int j = 0; j < 32; j++)
#pragma unroll
      for (int t2 = 0; t2 < 3; t2++) {
        int t1 = t12 - t2;
        if (t1 >= 0 && t1 < 3) s += W2s[(i * 32 + j) * 3 + t2] * W1s[(j * 2 + c) * 3 + t1];
      }
    M[i * 10 + c * 5 + t12] = s;
  }
  if (t >= 384 && t < 416) {
    int i = t - 384;
    float s = b2s[i];
    for (int j = 0; j < 32; j++) {
      float w = W2s[(i * 32 + j) * 3] + W2s[(i * 32 + j) * 3 + 1] + W2s[(i * 32 + j) * 3 + 2];
      s += w * b1s[j];
    }
    beta[i] = s;
  }
  __syncthreads();
  if (t < 448) {
    int o = t / 14, rem = t % 14, c = rem / 7, tt = rem % 7;
    float s = 0.f;
    for (int i = 0; i < 32; i++)
#pragma unroll
      for (int t3 = 0; t3 < 3; t3++) {
        int t12 = tt - t3;
        if (t12 >= 0 && t12 < 5) s += W3s[(o * 32 + i) * 3 + t3] * M[i * 10 + c * 5 + t12];
      }
    Kc[o * 14 + c * 7 + tt] = s;
  }
  if (t >= 480 && t < 512) {
    int o = t - 480;
    float s = b3s[o];
    for (int i = 0; i < 32; i++) {
      float w = W3s[(o * 32 + i) * 3] + W3s[(o * 32 + i) * 3 + 1] + W3s[(o * 32 + i) * 3 + 2];
      s += w * beta[i];
    }
    bconst[o] = s;
  }
}

// Kcb: bf16 A-operand table, rows padded K=14 -> 32 with zeros.
__global__ __launch_bounds__(256) void k_prepkb(const float* __restrict__ Kc,
                                                unsigned short* __restrict__ Kcb) {
  int idx = blockIdx.x * 256 + threadIdx.x;  // 0..1023
  int o = idx >> 5, k = idx & 31;
  Kcb[idx] = (k < 14) ? f2b(Kc[o * 14 + k]) : (unsigned short)0;
}

__global__ __launch_bounds__(64) void k_prepedge(
    const float* __restrict__ W1, const float* __restrict__ b1,
    const float* __restrict__ W2, const float* __restrict__ b2,
    const float* __restrict__ W3, const float* __restrict__ b3,
    float* __restrict__ edgeK, float* __restrict__ edgeB) {
  __shared__ float W1s[192], W2s[3072], W3s[3072];
  __shared__ float b1s[32], b2s[32], b3s[32];
  __shared__ float cl[2][6], h1[32][5], h2[32][4];
  const int t = threadIdx.x;
  const int side = blockIdx.x / 13, run = blockIdx.x % 13;
  for (int i = t; i < 3072; i += 64) { W2s[i] = W2[i]; W3s[i] = W3[i]; }
  for (int i = t; i < 192; i += 64) W1s[i] = W1[i];
  if (t < 32) { b1s[t] = b1[t]; b2s[t] = b2[t]; b3s[t] = b3[t]; }
  if (t < 12) cl[t / 6][t % 6] = (run == t) ? 1.f : 0.f;
  __syncthreads();
  const bool ub = (run == 12);
  if (t < 32) {
    int i = t;
    for (int p = 0; p < 5; p++) {
      float s = ub ? b1s[i] : 0.f;
      for (int c = 0; c < 2; c++)
#pragma unroll
        for (int tau = 0; tau < 3; tau++) {
          int x = (side == 0) ? (p + tau - 1) : (p + tau);
          if (x >= 0 && x < 6) s += W1s[(i * 2 + c) * 3 + tau] * cl[c][x];
        }
      h1[i][p] = s;
    }
  }
  __syncthreads();
  if (t < 32) {
    int o = t;
    for (int u = 0; u < 4; u++) {
      float s = ub ? b2s[o] : 0.f;
      for (int i = 0; i < 32; i++)
#pragma unroll
        for (int tau = 0; tau < 3; tau++) {
          int q = (side == 0) ? (u + tau - 1) : (u + tau);
          if (q >= 0 && q < 5) s += W2s[(o * 32 + i) * 3 + tau] * h1[i][q];
        }
      h2[o][u] = s;
    }
  }
  __syncthreads();
  if (t < 32) {
    int o = t;
    for (int e = 0; e < 2; e++) {
      float s = ub ? b3s[o] : 0.f;
      for (int i = 0; i < 32; i++)
#pragma unroll
        for (int tau = 0; tau < 3; tau++) {
          int u = (side == 0) ? (e + tau - 1) : (e + tau + 1);
          if (u >= 0 && u < 4) s += W3s[(o * 32 + i) * 3 + tau] * h2[i][u];
        }
      int slot = (side * 2 + e) * 32 + o;
      if (ub) edgeB[slot] = s;
      else edgeK[slot * 12 + run] = s;
    }
  }
}

// Wb in MFMA B-fragment order, bf16
__global__ __launch_bounds__(256) void k_prepw(const float* __restrict__ W,
                                               unsigned short* __restrict__ Wb) {
  int idx = blockIdx.x * 256 + threadIdx.x;
  int j = idx & 7;
  int lane = (idx >> 3) & 63;
  int nt = (idx >> 9) & 1;
  int kt = idx >> 10;
  int o = nt * 16 + (lane & 15);
  int k = kt * 32 + (lane >> 4) * 8 + j;
  int korig = (k & 31) * 384 + (k >> 5);
  Wb[idx] = f2b(W[(size_t)o * 12288 + korig]);
}

// ---------- fused CNN chain: MFMA composite conv + CBAM + pool ----------
__global__ __launch_bounds__(512) void k_cnn(
    const unsigned short* __restrict__ gout, const float* __restrict__ protein,
    const unsigned short* __restrict__ Kcb, const float* __restrict__ bconst,
    const float* __restrict__ edgeK, const float* __restrict__ edgeB,
    const float* __restrict__ caW1, const float* __restrict__ caW2,
    const float* __restrict__ samW, const float* __restrict__ samb,
    unsigned short* __restrict__ pvec) {
  __shared__ float combf[2][776];                  // comb[c][l+4], zero halo
  __shared__ alignas(16) unsigned short im2[768 * 16];  // im2col [l][k<16], bf16
  __shared__ float xbuf[2320];                     // xm@0, xM@772, att@1544
  __shared__ float bcs[32];
  __shared__ float wmaxs[8][32], wsums[8][32];
  __shared__ float cmaxs[32], csums[32], t1buf[2][16], feats[32], samWs[8];
  const int t = threadIdx.x;
  const int b = blockIdx.x;
  const int lane = t & 63, wv = t >> 6, lx = lane & 15, quad = lane >> 4;

  // S0a: stage comb (fp32) + small tables
  for (int i = t; i < 1552; i += 512) {
    int c = i / 776, li = i - c * 776;
    int l = li - 4;
    float v = 0.f;
    if (l >= 0 && l < LL)
      v = c ? protein[(size_t)b * LL + l] : b2f(gout[(size_t)b * LL + l]);
    combf[c][li] = v;
  }
  if (t < 32) bcs[t] = bconst[t];
  if (t >= 32 && t < 38) samWs[t - 32] = samW[t - 32];
  if (t == 38) samWs[6] = samb[0];
  __syncthreads();

  // S0b: build im2col bf16: im2[l*16+k] = comb[c][l + q - 3], c=k/7, q=k%7 (k<14)
  for (int p = 0; p < 24; p++) {
    int idx = t + p * 512;       // 0 .. 12287
    int l = idx >> 4, k = idx & 15;
    unsigned short v = 0;
    if (k < 14) {
      int c = (k >= 7) ? 1 : 0;
      int q = k - c * 7;
      v = f2b(combf[c][l + 1 + q]);
    }
    im2[idx] = v;
  }
  __syncthreads();

  // S1: MFMA conv: A = Kcb weights (M=16 x2 tiles), B = im2col; 6 n-tiles/wave
  f32x4 a3[6][2];
  {
    bf16x8 A0 = *(const bf16x8*)&Kcb[(0 * 16 + lx) * 32 + quad * 8];
    bf16x8 A1 = *(const bf16x8*)&Kcb[(1 * 16 + lx) * 32 + quad * 8];
    f32x4 ci0, ci1;
#pragma unroll
    for (int r = 0; r < 4; r++) {
      ci0[r] = bcs[quad * 4 + r];
      ci1[r] = bcs[16 + quad * 4 + r];
    }
#pragma unroll
    for (int n = 0; n < 6; n++) {
      int l = (wv * 6 + n) * 16 + lx;
      bf16x8 Bf = {0, 0, 0, 0, 0, 0, 0, 0};
      if (quad < 2) Bf = *(const bf16x8*)&im2[l * 16 + quad * 8];
      a3[n][0] = __builtin_amdgcn_mfma_f32_16x16x32_bf16(A0, Bf, ci0, 0, 0, 0);
      a3[n][1] = __builtin_amdgcn_mfma_f32_16x16x32_bf16(A1, Bf, ci1, 0, 0, 0);
    }
  }
  // edge fixup: l in {0,1} and {766,767} (fp32 comb, exact edge tables)
  {
    bool left = (wv == 0 && lx < 2);
    bool right = (wv == 7 && lx >= 14);
    if (left || right) {
      int n = left ? 0 : 5;
      int e = left ? lx : (lx - 14);
      int side = left ? 0 : 1;
      int cbase = left ? 4 : 766;
#pragma unroll
      for (int mt = 0; mt < 2; mt++)
#pragma unroll
        for (int r = 0; r < 4; r++) {
          int o = mt * 16 + quad * 4 + r;
          int slot = (side * 2 + e) * 32 + o;
          float s = edgeB[slot];
          const float* ek = &edgeK[slot * 12];
#pragma unroll
          for (int w = 0; w < 6; w++)
            s += ek[w] * combf[0][cbase + w] + ek[6 + w] * combf[1][cbase + w];
          a3[n][mt][r] = s;
        }
    }
  }

  // S3: channel stats
  float tmax[2][4], tsum[2][4];
#pragma unroll
  for (int mt = 0; mt < 2; mt++)
#pragma unroll
    for (int r = 0; r < 4; r++) { tmax[mt][r] = -1e30f; tsum[mt][r] = 0.f; }
#pragma unroll
  for (int n = 0; n < 6; n++)
#pragma unroll
    for (int mt = 0; mt < 2; mt++)
#pragma unroll
      for (int r = 0; r < 4; r++) {
        float v = a3[n][mt][r];
        tmax[mt][r] = fmaxf(tmax[mt][r], v);
        tsum[mt][r] += v;
      }
#pragma unroll
  for (int mt = 0; mt < 2; mt++)
#pragma unroll
    for (int r = 0; r < 4; r++) {
      float m = tmax[mt][r], s = tsum[mt][r];
      for (int d = 1; d < 16; d <<= 1) {
        m = fmaxf(m, __shfl_xor(m, d));
        s += __shfl_xor(s, d);
      }
      if (lx == 0) {
        wmaxs[wv][mt * 16 + quad * 4 + r] = m;
        wsums[wv][mt * 16 + quad * 4 + r] = s;
      }
    }
  __syncthreads();

  // S4: cross-wave stats + channel-attention MLP
  if (t < 32) {
    float m = wmaxs[0][t], s = wsums[0][t];
#pragma unroll
    for (int w = 1; w < 8; w++) { m = fmaxf(m, wmaxs[w][t]); s += wsums[w][t]; }
    cmaxs[t] = m;
    csums[t] = s;
  }
  __syncthreads();
  if (t < 32) {
    int j = t & 15;
    int mean = t >> 4;
    float s = 0.f;
    for (int o = 0; o < 32; o++) {
      float v = mean ? csums[o] * (1.f / 768.f) : cmaxs[o];
      s += v * caW1[j * 32 + o];
    }
    t1buf[mean][j] = s;
  }
  __syncthreads();
  if (t < 32) {
    float m1 = 0.f, m2 = 0.f;
    for (int j = 0; j < 16; j++) {
      m1 += t1buf[0][j] * caW2[t * 16 + j];
      m2 += t1buf[1][j] * caW2[t * 16 + j];
    }
    feats[t] = sigm(fmaxf(m1, 0.f) + fmaxf(m2, 0.f));
  }
  __syncthreads();

  // S5: spatial stats from registers
  float frq[2][4];
#pragma unroll
  for (int mt = 0; mt < 2; mt++)
#pragma unroll
    for (int r = 0; r < 4; r++) frq[mt][r] = feats[mt * 16 + quad * 4 + r];
#pragma unroll
  for (int n = 0; n < 6; n++) {
    int l = (wv * 6 + n) * 16 + lx;
    float sm = 0.f, mx = -1e30f;
#pragma unroll
    for (int mt = 0; mt < 2; mt++)
#pragma unroll
      for (int r = 0; r < 4; r++) {
        float v = a3[n][mt][r] * frq[mt][r];
        sm += v;
        mx = fmaxf(mx, v);
      }
    sm += __shfl_xor(sm, 16); mx = fmaxf(mx, __shfl_xor(mx, 16));
    sm += __shfl_xor(sm, 32); mx = fmaxf(mx, __shfl_xor(mx, 32));
    if (quad == 0) {
      xbuf[l] = sm * (1.f / 32.f);
      xbuf[772 + l] = mx;
    }
  }
  __syncthreads();

  // S6: spatial attention conv + sigmoid
  for (int l = t; l < LL; l += 512) {
    float a = samWs[6];
#pragma unroll
    for (int k = 0; k < 3; k++) {
      int ll = l + k - 1;
      float vm = (ll >= 0 && ll < LL) ? xbuf[ll] : 0.f;
      float vM = (ll >= 0 && ll < LL) ? xbuf[772 + ll] : 0.f;
      a += samWs[k] * vm + samWs[3 + k] * vM;
    }
    xbuf[1544 + l] = sigm(a);
  }
  __syncthreads();

  // S7: scale + maxpool2 via lane-pair shuffle, store pvec from registers
#pragma unroll
  for (int n = 0; n < 6; n++) {
    int l = (wv * 6 + n) * 16 + lx;
    float at = xbuf[1544 + l];
    float m[2][4];
#pragma unroll
    for (int mt = 0; mt < 2; mt++)
#pragma unroll
      for (int r = 0; r < 4; r++) {
        float v = a3[n][mt][r] * frq[mt][r] * at;
        m[mt][r] = fmaxf(v, __shfl_xor(v, 1));
      }
    if (!(lx & 1)) {
      int lp = l >> 1;
#pragma unroll
      for (int mt = 0; mt < 2; mt++) {
        uint2v pk;
        pk.x = f2b2(m[mt][0], m[mt][1]);
        pk.y = f2b2(m[mt][2], m[mt][3]);
        *(uint2v*)&pvec[(size_t)b * 12288 + lp * 32 + mt * 16 + quad * 4] = pk;
      }
    }
  }
}

// MLP layer-1 partials (MFMA): block = (32 graphs, 1/4 of K); 512 blocks.
__global__ __launch_bounds__(512) void k_mlp1(
    const unsigned short* __restrict__ pvec, const unsigned short* __restrict__ Wb,
    float* __restrict__ partial) {
  __shared__ float part[8][32][32];
  const int t = threadIdx.x;
  const int lane = t & 63, wv = t >> 6, lx = lane & 15, quad = lane >> 4;
  const int g0 = (blockIdx.x >> 2) * 32;
  const int kc = blockIdx.x & 3;
  const unsigned short* arow0 = pvec + (size_t)(g0 + lx) * 12288 + quad * 8;
  const unsigned short* arow1 = pvec + (size_t)(g0 + 16 + lx) * 12288 + quad * 8;

  f32x4 a00 = {0.f, 0.f, 0.f, 0.f}, a01 = a00, a10 = a00, a11 = a00;
  const int kt0 = kc * 96 + wv * 12;
#pragma unroll 4
  for (int i = 0; i < 12; i++) {
    const int kt = kt0 + i;
    bf16x8 A0 = *(const bf16x8*)&arow0[kt * 32];
    bf16x8 A1 = *(const bf16x8*)&arow1[kt * 32];
    bf16x8 B0 = *(const bf16x8*)&Wb[((kt * 2 + 0) * 64 + lane) * 8];
    bf16x8 B1 = *(const bf16x8*)&Wb[((kt * 2 + 1) * 64 + lane) * 8];
    a00 = __builtin_amdgcn_mfma_f32_16x16x32_bf16(A0, B0, a00, 0, 0, 0);
    a01 = __builtin_amdgcn_mfma_f32_16x16x32_bf16(A0, B1, a01, 0, 0, 0);
    a10 = __builtin_amdgcn_mfma_f32_16x16x32_bf16(A1, B0, a10, 0, 0, 0);
    a11 = __builtin_amdgcn_mfma_f32_16x16x32_bf16(A1, B1, a11, 0, 0, 0);
  }
#pragma unroll
  for (int r = 0; r < 4; r++) {
    part[wv][quad * 4 + r][lx]            = a00[r];
    part[wv][quad * 4 + r][16 + lx]       = a01[r];
    part[wv][16 + quad * 4 + r][lx]       = a10[r];
    part[wv][16 + quad * 4 + r][16 + lx]  = a11[r];
  }
  __syncthreads();
#pragma unroll
  for (int p = 0; p < 2; p++) {
    int idx = t + p * 512;  // 0..1023
    int g = idx >> 5, o = idx & 31;
    float s = 0.f;
#pragma unroll
    for (int w = 0; w < 8; w++) s += part[w][g][o];
    partial[((size_t)kc * BB + g0 + g) * 32 + o] = s;
  }
}

// MLP tail: reduce 4 K-chunk partials + softplus chain + layers 2,3.
__global__ __launch_bounds__(512) void k_mlp2(
    const float* __restrict__ partial,
    const float* __restrict__ lb1, const float* __restrict__ W2,
    const float* __restrict__ lb2, const float* __restrict__ W3,
    const float* __restrict__ lb3, float* __restrict__ out) {
  __shared__ float s1[16][32];
  __shared__ float s2[16][32];
  const int t = threadIdx.x;
  const int g0 = blockIdx.x * 16;
  {
    int g = t >> 5, o = t & 31;
    float s = lb1[o];
#pragma unroll
    for (int kc = 0; kc < 4; kc++) s += partial[((size_t)kc * BB + g0 + g) * 32 + o];
    s1[g][o] = softplus_(s);
  }
  __syncthreads();
  {
    int g = t >> 5, o = t & 31;
    float s = lb2[o];
    for (int kk = 0; kk < 32; kk++) s += s1[g][kk] * W2[o * 32 + kk];
    s2[g][o] = softplus_(s);
  }
  __syncthreads();
  if (t < 16) {
    float s = lb3[0];
    for (int kk = 0; kk < 32; kk++) s += s2[t][kk] * W3[kk];
    out[g0 + t] = softplus_(s);
  }
}

extern "C" void kernel_launch(void* const* d_in, const int* in_sizes, int n_in,
                              void* d_out, int out_size, void* d_ws, size_t ws_size,
                              hipStream_t stream) {
  const float* drug    = (const float*)d_in[0];
  const int*   ei      = (const int*)d_in[1];
  const float* protein = (const float*)d_in[3];
  const float* g1W = (const float*)d_in[4];
  const float* g1b = (const float*)d_in[5];
  const float* g2W = (const float*)d_in[6];
  const float* g2b = (const float*)d_in[7];
  const float* oW  = (const float*)d_in[8];
  const float* ob  = (const float*)d_in[9];
  const float* c1W = (const float*)d_in[10];
  const float* c1b = (const float*)d_in[11];
  const float* c2W = (const float*)d_in[12];
  const float* c2b = (const float*)d_in[13];
  const float* c3W = (const float*)d_in[14];
  const float* c3b = (const float*)d_in[15];
  const float* caW1 = (const float*)d_in[16];
  const float* caW2 = (const float*)d_in[17];
  const float* samW = (const float*)d_in[18];
  const float* samb = (const float*)d_in[19];
  const float* l1W = (const float*)d_in[20];
  const float* l1b = (const float*)d_in[21];
  const float* l2W = (const float*)d_in[22];
  const float* l2b = (const float*)d_in[23];
  const float* l3W = (const float*)d_in[24];
  const float* l3b = (const float*)d_in[25];

  // ---- workspace map: peak exactly 112 MiB (known-safe) ----
  char* ws = (char*)d_ws;
  float* dinv  = (float*)(ws);                        // [0, 0.5M)
  int*   degi  = (int*)(ws + (size_t)524288);         // [0.5M, 1M)
  int*   cur   = (int*)(ws + (size_t)1048576);        // [1M, 1.5M)
  int*   offs  = (int*)(ws + (size_t)1572864);        // [1.5M, 2M+4)
  int*   bsum  = (int*)(ws + (size_t)2621440);
  int*   bexcl = (int*)(ws + (size_t)2625536);
  int*   csr   = (int*)(ws + (size_t)3145728);        // [3M, 5M)
  unsigned short* gA = (unsigned short*)(ws + (size_t)5242880);   // [5M, 21M)
  unsigned short* gB = (unsigned short*)(ws + (size_t)22020096);  // [21M, 37M)
  unsigned short* pvec = (unsigned short*)(ws + (size_t)5242880); // overlays gA/gB
  float* pooled = (float*)(ws + (size_t)105906176);   // [101M, 103M)
  unsigned short* gout = (unsigned short*)(ws + (size_t)108003328);  // [103M, 109M)
  unsigned short* Wb   = (unsigned short*)(ws + (size_t)114294784);  // 768K
  float* Kc      = (float*)(ws + (size_t)115081216);  // 1792 B
  float* bconst  = (float*)(ws + (size_t)115083136);  // 128 B
  float* edgeK   = (float*)(ws + (size_t)115083264);  // 6144 B
  float* edgeB   = (float*)(ws + (size_t)115089408);  // 512 B
  unsigned short* Kcb = (unsigned short*)(ws + (size_t)115090432); // 2048 B
  float* partial = (float*)(ws + (size_t)115343360);  // 2 MiB, ends at 112 MiB
  float* outp = (float*)d_out;

  // ---- CSR build + precompute ----
  k_zeroi<<<2 * NN / 256, 256, 0, stream>>>(degi);
  k_hist<<<EE / 256, 256, 0, stream>>>(ei, degi);
  k_dinv<<<NN / 256, 256, 0, stream>>>(degi, dinv);
  k_scan1<<<NN / 256, 256, 0, stream>>>(degi, offs, bsum);
  k_scan2<<<1, 512, 0, stream>>>(bsum, bexcl);
  k_scan3<<<NN / 256, 256, 0, stream>>>(offs, degi, bexcl, offs);
  k_scatter<<<EE / 256, 256, 0, stream>>>(ei, offs, cur, csr);
  k_prepw<<<(12288 * 32) / 256, 256, 0, stream>>>(l1W, Wb);
  k_prepk7<<<1, 512, 0, stream>>>(c1W, c1b, c2W, c2b, c3W, c3b, Kc, bconst);
  k_prepkb<<<4, 256, 0, stream>>>(Kc, Kcb);
  k_prepedge<<<26, 64, 0, stream>>>(c1W, c1b, c2W, c2b, c3W, c3b, edgeK, edgeB);

  // ---- GCN ----
  k_mm1<<<NN / 4, 256, 0, stream>>>(drug, g1W, dinv, gA);
  k_layer<true><<<NN / 4, 256, 0, stream>>>(gA, offs, csr, dinv, g1b, g2W, gB);
  k_layer<true><<<NN / 4, 256, 0, stream>>>(gB, offs, csr, dinv, g2b, g2W, gA);
  k_lastpool<<<BB, 512, 0, stream>>>(gA, offs, csr, dinv, g2b, pooled);

  // ---- output linear ----
  k_outmm<<<BB / 16, 256, 0, stream>>>(pooled, oW, ob, gout);

  // ---- fused CNN chain (MFMA composite conv) + CBAM + maxpool ----
  k_cnn<<<BB, 512, 0, stream>>>(gout, protein, Kcb, bconst, edgeK, edgeB,
                                caW1, caW2, samW, samb, pvec);

  // ---- MLP head (MFMA, 32 graphs/block, K-split 4x) ----
  k_mlp1<<<(BB / 32) * 4, 512, 0, stream>>>(pvec, Wb, partial);
  k_mlp2<<<BB / 16, 512, 0, stream>>>(partial, l1b, l2W, l2b, l3W, l3b, outp);
}

// Round 13
// 581.217 us; speedup vs baseline: 1.4278x; 1.2023x over previous
//
#include <hip/hip_runtime.h>
#include <cstdint>
#include <cstddef>

#define NN 131072
#define EE 524288
#define BB 4096
#define LL 768

typedef __attribute__((ext_vector_type(8))) short bf16x8;
typedef __attribute__((ext_vector_type(4))) float f32x4;
typedef __attribute__((ext_vector_type(2))) unsigned int uint2v;

// ---------- helpers ----------
__device__ __forceinline__ float b2f(unsigned short u) {
  return __uint_as_float(((unsigned int)u) << 16);
}
__device__ __forceinline__ unsigned short f2b(float f) {
  unsigned int x = __float_as_uint(f);
  x += 0x7fff + ((x >> 16) & 1);  // RNE
  return (unsigned short)(x >> 16);
}
__device__ __forceinline__ unsigned f2b2(float lo, float hi) {
#if __has_builtin(__builtin_amdgcn_cvt_pk_bf16_f32)
  typedef __attribute__((ext_vector_type(2))) __bf16 bf16v2;
  bf16v2 r = __builtin_amdgcn_cvt_pk_bf16_f32(lo, hi);
  return __builtin_bit_cast(unsigned, r);
#else
  return (unsigned)f2b(lo) | ((unsigned)f2b(hi) << 16);
#endif
}
__device__ __forceinline__ float sigm(float x) { return 1.f / (1.f + expf(-x)); }
__device__ __forceinline__ float softplus_(float x) {
  return fmaxf(x, 0.f) + log1pf(expf(-fabsf(x)));
}

// ---------- CSR build ----------
__global__ __launch_bounds__(256) void k_zeroi(int* __restrict__ p) {
  p[blockIdx.x * 256 + threadIdx.x] = 0;
}
__global__ __launch_bounds__(256) void k_hist(const int* __restrict__ ei,
                                              int* __restrict__ degi) {
  int e = blockIdx.x * 256 + threadIdx.x;
  atomicAdd(&degi[ei[EE + e]], 1);
}
__global__ __launch_bounds__(256) void k_scan1(const int* __restrict__ degi,
                                               int* __restrict__ incl,
                                               int* __restrict__ bsum) {
  __shared__ int s[256];
  int t = threadIdx.x;
  int i = blockIdx.x * 256 + t;
  s[t] = degi[i];
  __syncthreads();
  for (int off = 1; off < 256; off <<= 1) {
    int u = (t >= off) ? s[t - off] : 0;
    __syncthreads();
    s[t] += u;
    __syncthreads();
  }
  incl[i] = s[t];
  if (t == 255) bsum[blockIdx.x] = s[t];
}
__global__ __launch_bounds__(512) void k_scan2(const int* __restrict__ bsum,
                                               int* __restrict__ bexcl) {
  __shared__ int s[512];
  int t = threadIdx.x;
  s[t] = bsum[t];
  __syncthreads();
  int orig = s[t];
  for (int off = 1; off < 512; off <<= 1) {
    int u = (t >= off) ? s[t - off] : 0;
    __syncthreads();
    s[t] += u;
    __syncthreads();
  }
  bexcl[t] = s[t] - orig;
}
// scan3 + dinv fused
__global__ __launch_bounds__(256) void k_scan3(const int* __restrict__ incl,
                                               const int* __restrict__ degi,
                                               const int* __restrict__ bexcl,
                                               int* __restrict__ offs,
                                               float* __restrict__ dinv) {
  int t = threadIdx.x;
  int i = blockIdx.x * 256 + t;
  offs[i] = incl[i] - degi[i] + bexcl[blockIdx.x];
  dinv[i] = rsqrtf((float)degi[i] + 1.0f);
  if (i == 0) offs[NN] = EE;
}
__global__ __launch_bounds__(256) void k_scatter(const int* __restrict__ ei,
                                                 const int* __restrict__ offs,
                                                 int* __restrict__ cur,
                                                 int* __restrict__ csr) {
  int e = blockIdx.x * 256 + threadIdx.x;
  int dst = ei[EE + e];
  int pos = atomicAdd(&cur[dst], 1);
  csr[offs[dst] + pos] = ei[e];
}

// ---------- GCN (bf16 feature buffers) ----------
__global__ __launch_bounds__(256) void k_mm1(const float* __restrict__ drug,
                                             const float* __restrict__ W,
                                             const float* __restrict__ dinv,
                                             unsigned short* __restrict__ g) {
  __shared__ float Ws[9 * 64];
  int t = threadIdx.x;
  for (int i = t; i < 576; i += 256) Ws[i] = W[i];
  __syncthreads();
  int node = blockIdx.x * 4 + (t >> 6);
  int f = t & 63;
  const float* dr = drug + (size_t)node * 9;
  float s = 0.f;
#pragma unroll
  for (int k = 0; k < 9; k++) s += dr[k] * Ws[k * 64 + f];
  g[(size_t)node * 64 + f] = f2b(dinv[node] * s);
}

// Wgb: g2W in MFMA B-fragment order: idx=((kc*4+nt)*64+lane)*8+j ->
// W[k][o], k=kc*32+(lane>>4)*8+j, o=nt*16+(lane&15). 4096 bf16 (8 KB).
__global__ __launch_bounds__(256) void k_prepg(const float* __restrict__ W,
                                               unsigned short* __restrict__ Wgb) {
  int idx = blockIdx.x * 256 + threadIdx.x;  // 0..4095
  int j = idx & 7;
  int lane = (idx >> 3) & 63;
  int nt = (idx >> 9) & 3;
  int kc = idx >> 11;
  int k = kc * 32 + (lane >> 4) * 8 + j;
  int o = nt * 16 + (lane & 15);
  Wgb[idx] = f2b(W[k * 64 + o]);
}

// CSR pull aggregation (32 nodes/block) + MFMA 64x64 matmul -> bf16 out.
template <bool TANH>
__global__ __launch_bounds__(256) void k_layer(const unsigned short* __restrict__ gin,
                                               const int* __restrict__ offs,
                                               const int* __restrict__ csr,
                                               const float* __restrict__ dinv,
                                               const float* __restrict__ bias,
                                               const unsigned short* __restrict__ Wgb,
                                               unsigned short* __restrict__ outb) {
  __shared__ alignas(16) unsigned short xa[32 * 72];  // bf16, stride 72 (bank-safe)
  __shared__ alignas(16) float dis[32];
  const int t = threadIdx.x;
  const int wv = t >> 6, f = t & 63;
  const int lx = f & 15, quad = f >> 4;
  const int n0 = blockIdx.x * 32;
  const float bf = bias[f];
  // Phase A: aggregate 8 nodes per wave, lane = feature
  for (int it = 0; it < 8; it++) {
    const int dl = wv * 8 + it;
    const int d = n0 + dl;
    const float di = dinv[d];
    const int j0 = offs[d], j1 = offs[d + 1];
    float acc = b2f(gin[(size_t)d * 64 + f]);
    int j = j0;
    for (; j + 4 <= j1; j += 4) {
      int s0 = csr[j], s1 = csr[j + 1], s2 = csr[j + 2], s3 = csr[j + 3];
      acc += (b2f(gin[(size_t)s0 * 64 + f]) + b2f(gin[(size_t)s1 * 64 + f]))
           + (b2f(gin[(size_t)s2 * 64 + f]) + b2f(gin[(size_t)s3 * 64 + f]));
    }
    for (; j < j1; j++) acc += b2f(gin[(size_t)csr[j] * 64 + f]);
    float v = di * acc + bf;
    if (TANH) v = tanhf(v);
    xa[dl * 72 + f] = f2b(v);
    if (f == 0) dis[dl] = di;
  }
  __syncthreads();
  // Phase B: [32x64] @ W[64x64] via MFMA. wave -> (mt = wv>>1, np = wv&1)
  const int mt = wv >> 1, np = wv & 1;
  bf16x8 A0 = *(const bf16x8*)&xa[(mt * 16 + lx) * 72 + quad * 8];
  bf16x8 A1 = *(const bf16x8*)&xa[(mt * 16 + lx) * 72 + 32 + quad * 8];
  f32x4 accs[2];
#pragma unroll
  for (int nn = 0; nn < 2; nn++) {
    int nt = np * 2 + nn;
    bf16x8 B0 = *(const bf16x8*)&Wgb[((0 * 4 + nt) * 64 + f) * 8];
    bf16x8 B1 = *(const bf16x8*)&Wgb[((1 * 4 + nt) * 64 + f) * 8];
    f32x4 acc = {0.f, 0.f, 0.f, 0.f};
    acc = __builtin_amdgcn_mfma_f32_16x16x32_bf16(A0, B0, acc, 0, 0, 0);
    acc = __builtin_amdgcn_mfma_f32_16x16x32_bf16(A1, B1, acc, 0, 0, 0);
    accs[nn] = acc;
  }
  f32x4 dq = *(const f32x4*)&dis[mt * 16 + quad * 4];
  __syncthreads();  // all A-frag reads complete before overwrite
#pragma unroll
  for (int nn = 0; nn < 2; nn++) {
    int nt = np * 2 + nn;
#pragma unroll
    for (int r = 0; r < 4; r++)
      xa[(mt * 16 + quad * 4 + r) * 72 + nt * 16 + lx] = f2b(dq[r] * accs[nn][r]);
  }
  __syncthreads();
  // coalesced writeout: 256 chunks of 16 B
  {
    int node = t >> 3, c8 = t & 7;
    *(f32x4*)(outb + (size_t)(n0 + node) * 64 + c8 * 8) =
        *(const f32x4*)(xa + node * 72 + c8 * 8);
  }
}

__global__ __launch_bounds__(512) void k_lastpool(const unsigned short* __restrict__ gin,
                                                  const int* __restrict__ offs,
                                                  const int* __restrict__ csr,
                                                  const float* __restrict__ dinv,
                                                  const float* __restrict__ bias,
                                                  float* __restrict__ pooled) {
  __shared__ float smax[8][64], ssum[8][64];
  const int t = threadIdx.x;
  const int f = t & 63, grp = t >> 6;
  const int g = blockIdx.x;
  const float bf = bias[f];
  float mx = -1e30f, sm = 0.f;
#pragma unroll
  for (int i = 0; i < 4; i++) {
    int d = g * 32 + grp * 4 + i;
    const float di = dinv[d];
    const int j0 = offs[d], j1 = offs[d + 1];
    float acc = b2f(gin[(size_t)d * 64 + f]);
    int j = j0;
    for (; j + 4 <= j1; j += 4) {
      int s0 = csr[j], s1 = csr[j + 1], s2 = csr[j + 2], s3 = csr[j + 3];
      acc += (b2f(gin[(size_t)s0 * 64 + f]) + b2f(gin[(size_t)s1 * 64 + f]))
           + (b2f(gin[(size_t)s2 * 64 + f]) + b2f(gin[(size_t)s3 * 64 + f]));
    }
    for (; j < j1; j++) acc += b2f(gin[(size_t)csr[j] * 64 + f]);
    float v = di * acc + bf;
    mx = fmaxf(mx, v);
    sm += v;
  }
  smax[grp][f] = mx;
  ssum[grp][f] = sm;
  __syncthreads();
  if (t < 64) {
    float m = smax[0][t], s = ssum[0][t];
#pragma unroll
    for (int w = 1; w < 8; w++) { m = fmaxf(m, smax[w][t]); s += ssum[w][t]; }
    pooled[(size_t)g * 128 + t] = m;
    pooled[(size_t)g * 128 + 64 + t] = s * (1.f / 32.f);
  }
}

// gout(bf16): 16 graphs/block
__global__ __launch_bounds__(256) void k_outmm(const float* __restrict__ pooled,
                                               const float* __restrict__ W,
                                               const float* __restrict__ bias,
                                               unsigned short* __restrict__ gout) {
  __shared__ float ps[16][128];
  int t = threadIdx.x;
  int g0 = blockIdx.x * 16;
  for (int i = t; i < 16 * 128; i += 256) ps[i >> 7][i & 127] = pooled[(size_t)g0 * 128 + i];
  __syncthreads();
  float a0[16], a1[16], a2[16];
#pragma unroll
  for (int j = 0; j < 16; j++) { a0[j] = 0.f; a1[j] = 0.f; a2[j] = 0.f; }
  for (int k = 0; k < 128; k++) {
    float w0 = W[k * 768 + t];
    float w1 = W[k * 768 + t + 256];
    float w2 = W[k * 768 + t + 512];
#pragma unroll
    for (int j = 0; j < 16; j++) {
      float p = ps[j][k];
      a0[j] += p * w0; a1[j] += p * w1; a2[j] += p * w2;
    }
  }
  float b0 = bias[t], b1 = bias[t + 256], b2 = bias[t + 512];
  for (int j = 0; j < 16; j++) {
    gout[(size_t)(g0 + j) * 768 + t]       = f2b(a0[j] + b0);
    gout[(size_t)(g0 + j) * 768 + t + 256] = f2b(a1[j] + b1);
    gout[(size_t)(g0 + j) * 768 + t + 512] = f2b(a2[j] + b2);
  }
}

// ---------- composite conv precompute (emits bf16 A-frag table directly) ----------
__global__ __launch_bounds__(512) void k_prepk7(
    const float* __restrict__ W1, const float* __restrict__ b1,
    const float* __restrict__ W2, const float* __restrict__ b2,
    const float* __restrict__ W3, const float* __restrict__ b3,
    unsigned short* __restrict__ Kcb, float* __restrict__ bconst) {
  __shared__ float W1s[192], W2s[3072], W3s[3072];
  __shared__ float b1s[32], b2s[32], b3s[32];
  __shared__ float M[320];
  __shared__ float beta[32];
  __shared__ float KcS[448];
  const int t = threadIdx.x;
  for (int i = t; i < 3072; i += 512) { W2s[i] = W2[i]; W3s[i] = W3[i]; }
  if (t < 192) W1s[t] = W1[t];
  if (t >= 192 && t < 224) { int i = t - 192; b1s[i] = b1[i]; b2s[i] = b2[i]; b3s[i] = b3[i]; }
  __syncthreads();
  if (t < 320) {
    int i = t / 10, rem = t % 10, c = rem / 5, t12 = rem % 5;
    float s = 0.f;
    for (int j = 0; j < 32; j++)
#pragma unroll
      for (int t2 = 0; t2 < 3; t2++) {
        int t1 = t12 - t2;
        if (t1 >= 0 && t1 < 3) s += W2s[(i * 32 + j) * 3 + t2] * W1s[(j * 2 + c) * 3 + t1];
      }
    M[i * 10 + c * 5 + t12] = s;
  }
  if (t >= 384 && t < 416) {
    int i = t - 384;
    float s = b2s[i];
    for (int j = 0; j < 32; j++) {
      float w = W2s[(i * 32 + j) * 3] + W2s[(i * 32 + j) * 3 + 1] + W2s[(i * 32 + j) * 3 + 2];
      s += w * b1s[j];
    }
    beta[i] = s;
  }
  __syncthreads();
  if (t < 448) {
    int o = t / 14, rem = t % 14, c = rem / 7, tt = rem % 7;
    float s = 0.f;
    for (int i = 0; i < 32; i++)
#pragma unroll
      for (int t3 = 0; t3 < 3; t3++) {
        int t12 = tt - t3;
        if (t12 >= 0 && t12 < 5) s += W3s[(o * 32 + i) * 3 + t3] * M[i * 10 + c * 5 + t12];
      }
    KcS[t] = s;
  }
  if (t >= 480 && t < 512) {
    int o = t - 480;
    float s = b3s[o];
    for (int i = 0; i < 32; i++) {
      float w = W3s[(o * 32 + i) * 3] + W3s[(o * 32 + i) * 3 + 1] + W3s[(o * 32 + i) * 3 + 2];
      s += w * beta[i];
    }
    bconst[o] = s;
  }
  __syncthreads();
  for (int i = t; i < 1024; i += 512) {
    int o = i >> 5, k = i & 31;
    Kcb[i] = (k < 14) ? f2b(KcS[o * 14 + k]) : (unsigned short)0;
  }
}

__global__ __launch_bounds__(64) void k_prepedge(
    const float* __restrict__ W1, const float* __restrict__ b1,
    const float* __restrict__ W2, const float* __restrict__ b2,
    const float* __restrict__ W3, const float* __restrict__ b3,
    float* __restrict__ edgeK, float* __restrict__ edgeB) {
  __shared__ float W1s[192], W2s[3072], W3s[3072];
  __shared__ float b1s[32], b2s[32], b3s[32];
  __shared__ float cl[2][6], h1[32][5], h2[32][4];
  const int t = threadIdx.x;
  const int side = blockIdx.x / 13, run = blockIdx.x % 13;
  for (int i = t; i < 3072; i += 64) { W2s[i] = W2[i]; W3s[i] = W3[i]; }
  for (int i = t; i < 192; i += 64) W1s[i] = W1[i];
  if (t < 32) { b1s[t] = b1[t]; b2s[t] = b2[t]; b3s[t] = b3[t]; }
  if (t < 12) cl[t / 6][t % 6] = (run == t) ? 1.f : 0.f;
  __syncthreads();
  const bool ub = (run == 12);
  if (t < 32) {
    int i = t;
    for (int p = 0; p < 5; p++) {
      float s = ub ? b1s[i] : 0.f;
      for (int c = 0; c < 2; c++)
#pragma unroll
        for (int tau = 0; tau < 3; tau++) {
          int x = (side == 0) ? (p + tau - 1) : (p + tau);
          if (x >= 0 && x < 6) s += W1s[(i * 2 + c) * 3 + tau] * cl[c][x];
        }
      h1[i][p] = s;
    }
  }
  __syncthreads();
  if (t < 32) {
    int o = t;
    for (int u = 0; u < 4; u++) {
      float s = ub ? b2s[o] : 0.f;
      for (int i = 0; i < 32; i++)
#pragma unroll
        for (int tau = 0; tau < 3; tau++) {
          int q = (side == 0) ? (u + tau - 1) : (u + tau);
          if (q >= 0 && q < 5) s += W2s[(o * 32 + i) * 3 + tau] * h1[i][q];
        }
      h2[o][u] = s;
    }
  }
  __syncthreads();
  if (t < 32) {
    int o = t;
    for (int e = 0; e < 2; e++) {
      float s = ub ? b3s[o] : 0.f;
      for (int i = 0; i < 32; i++)
#pragma unroll
        for (int tau = 0; tau < 3; tau++) {
          int u = (side == 0) ? (e + tau - 1) : (e + tau + 1);
          if (u >= 0 && u < 4) s += W3s[(o * 32 + i) * 3 + tau] * h2[i][u];
        }
      int slot = (side * 2 + e) * 32 + o;
      if (ub) edgeB[slot] = s;
      else edgeK[slot * 12 + run] = s;
    }
  }
}

// Wb in MFMA B-fragment order, bf16
__global__ __launch_bounds__(256) void k_prepw(const float* __restrict__ W,
                                               unsigned short* __restrict__ Wb) {
  int idx = blockIdx.x * 256 + threadIdx.x;
  int j = idx & 7;
  int lane = (idx >> 3) & 63;
  int nt = (idx >> 9) & 1;
  int kt = idx >> 10;
  int o = nt * 16 + (lane & 15);
  int k = kt * 32 + (lane >> 4) * 8 + j;
  int korig = (k & 31) * 384 + (k >> 5);
  Wb[idx] = f2b(W[(size_t)o * 12288 + korig]);
}

// ---------- fused CNN chain: MFMA composite conv + CBAM + pool ----------
__global__ __launch_bounds__(512) void k_cnn(
    const unsigned short* __restrict__ gout, const float* __restrict__ protein,
    const unsigned short* __restrict__ Kcb, const float* __restrict__ bconst,
    const float* __restrict__ edgeK, const float* __restrict__ edgeB,
    const float* __restrict__ caW1, const float* __restrict__ caW2,
    const float* __restrict__ samW, const float* __restrict__ samb,
    unsigned short* __restrict__ pvec) {
  __shared__ float combf[2][776];                  // comb[c][l+4], zero halo
  __shared__ alignas(16) unsigned short im2[768 * 16];  // im2col [l][k<16], bf16
  __shared__ float xbuf[2320];                     // xm@0, xM@772, att@1544
  __shared__ float bcs[32];
  __shared__ float wmaxs[8][32], wsums[8][32];
  __shared__ float cmaxs[32], csums[32], t1buf[2][16], feats[32], samWs[8];
  const int t = threadIdx.x;
  const int b = blockIdx.x;
  const int lane = t & 63, wv = t >> 6, lx = lane & 15, quad = lane >> 4;

  // S0a: stage comb (fp32) + small tables
  for (int i = t; i < 1552; i += 512) {
    int c = i / 776, li = i - c * 776;
    int l = li - 4;
    float v = 0.f;
    if (l >= 0 && l < LL)
      v = c ? protein[(size_t)b * LL + l] : b2f(gout[(size_t)b * LL + l]);
    combf[c][li] = v;
  }
  if (t < 32) bcs[t] = bconst[t];
  if (t >= 32 && t < 38) samWs[t - 32] = samW[t - 32];
  if (t == 38) samWs[6] = samb[0];
  __syncthreads();

  // S0b: build im2col bf16
  for (int p = 0; p < 24; p++) {
    int idx = t + p * 512;
    int l = idx >> 4, k = idx & 15;
    unsigned short v = 0;
    if (k < 14) {
      int c = (k >= 7) ? 1 : 0;
      int q = k - c * 7;
      v = f2b(combf[c][l + 1 + q]);
    }
    im2[idx] = v;
  }
  __syncthreads();

  // S1: MFMA conv
  f32x4 a3[6][2];
  {
    bf16x8 A0 = *(const bf16x8*)&Kcb[(0 * 16 + lx) * 32 + quad * 8];
    bf16x8 A1 = *(const bf16x8*)&Kcb[(1 * 16 + lx) * 32 + quad * 8];
    f32x4 ci0, ci1;
#pragma unroll
    for (int r = 0; r < 4; r++) {
      ci0[r] = bcs[quad * 4 + r];
      ci1[r] = bcs[16 + quad * 4 + r];
    }
#pragma unroll
    for (int n = 0; n < 6; n++) {
      int l = (wv * 6 + n) * 16 + lx;
      bf16x8 Bf = {0, 0, 0, 0, 0, 0, 0, 0};
      if (quad < 2) Bf = *(const bf16x8*)&im2[l * 16 + quad * 8];
      a3[n][0] = __builtin_amdgcn_mfma_f32_16x16x32_bf16(A0, Bf, ci0, 0, 0, 0);
      a3[n][1] = __builtin_amdgcn_mfma_f32_16x16x32_bf16(A1, Bf, ci1, 0, 0, 0);
    }
  }
  // edge fixup
  {
    bool left = (wv == 0 && lx < 2);
    bool right = (wv == 7 && lx >= 14);
    if (left || right) {
      int n = left ? 0 : 5;
      int e = left ? lx : (lx - 14);
      int side = left ? 0 : 1;
      int cbase = left ? 4 : 766;
#pragma unroll
      for (int mt = 0; mt < 2; mt++)
#pragma unroll
        for (int r = 0; r < 4; r++) {
          int o = mt * 16 + quad * 4 + r;
          int slot = (side * 2 + e) * 32 + o;
          float s = edgeB[slot];
          const float* ek = &edgeK[slot * 12];
#pragma unroll
          for (int w = 0; w < 6; w++)
            s += ek[w] * combf[0][cbase + w] + ek[6 + w] * combf[1][cbase + w];
          a3[n][mt][r] = s;
        }
    }
  }

  // S3: channel stats
  float tmax[2][4], tsum[2][4];
#pragma unroll
  for (int mt = 0; mt < 2; mt++)
#pragma unroll
    for (int r = 0; r < 4; r++) { tmax[mt][r] = -1e30f; tsum[mt][r] = 0.f; }
#pragma unroll
  for (int n = 0; n < 6; n++)
#pragma unroll
    for (int mt = 0; mt < 2; mt++)
#pragma unroll
      for (int r = 0; r < 4; r++) {
        float v = a3[n][mt][r];
        tmax[mt][r] = fmaxf(tmax[mt][r], v);
        tsum[mt][r] += v;
      }
#pragma unroll
  for (int mt = 0; mt < 2; mt++)
#pragma unroll
    for (int r = 0; r < 4; r++) {
      float m = tmax[mt][r], s = tsum[mt][r];
      for (int d = 1; d < 16; d <<= 1) {
        m = fmaxf(m, __shfl_xor(m, d));
        s += __shfl_xor(s, d);
      }
      if (lx == 0) {
        wmaxs[wv][mt * 16 + quad * 4 + r] = m;
        wsums[wv][mt * 16 + quad * 4 + r] = s;
      }
    }
  __syncthreads();

  // S4: cross-wave stats + channel-attention MLP
  if (t < 32) {
    float m = wmaxs[0][t], s = wsums[0][t];
#pragma unroll
    for (int w = 1; w < 8; w++) { m = fmaxf(m, wmaxs[w][t]); s += wsums[w][t]; }
    cmaxs[t] = m;
    csums[t] = s;
  }
  __syncthreads();
  if (t < 32) {
    int j = t & 15;
    int mean = t >> 4;
    float s = 0.f;
    for (int o = 0; o < 32; o++) {
      float v = mean ? csums[o] * (1.f / 768.f) : cmaxs[o];
      s += v * caW1[j * 32 + o];
    }
    t1buf[mean][j] = s;
  }
  __syncthreads();
  if (t < 32) {
    float m1 = 0.f, m2 = 0.f;
    for (int j = 0; j < 16; j++) {
      m1 += t1buf[0][j] * caW2[t * 16 + j];
      m2 += t1buf[1][j] * caW2[t * 16 + j];
    }
    feats[t] = sigm(fmaxf(m1, 0.f) + fmaxf(m2, 0.f));
  }
  __syncthreads();

  // S5: spatial stats from registers
  float frq[2][4];
#pragma unroll
  for (int mt = 0; mt < 2; mt++)
#pragma unroll
    for (int r = 0; r < 4; r++) frq[mt][r] = feats[mt * 16 + quad * 4 + r];
#pragma unroll
  for (int n = 0; n < 6; n++) {
    int l = (wv * 6 + n) * 16 + lx;
    float sm = 0.f, mx = -1e30f;
#pragma unroll
    for (int mt = 0; mt < 2; mt++)
#pragma unroll
      for (int r = 0; r < 4; r++) {
        float v = a3[n][mt][r] * frq[mt][r];
        sm += v;
        mx = fmaxf(mx, v);
      }
    sm += __shfl_xor(sm, 16); mx = fmaxf(mx, __shfl_xor(mx, 16));
    sm += __shfl_xor(sm, 32); mx = fmaxf(mx, __shfl_xor(mx, 32));
    if (quad == 0) {
      xbuf[l] = sm * (1.f / 32.f);
      xbuf[772 + l] = mx;
    }
  }
  __syncthreads();

  // S6: spatial attention conv + sigmoid
  for (int l = t; l < LL; l += 512) {
    float a = samWs[6];
#pragma unroll
    for (int k = 0; k < 3; k++) {
      int ll = l + k - 1;
      float vm = (ll >= 0 && ll < LL) ? xbuf[ll] : 0.f;
      float vM = (ll >= 0 && ll < LL) ? xbuf[772 + ll] : 0.f;
      a += samWs[k] * vm + samWs[3 + k] * vM;
    }
    xbuf[1544 + l] = sigm(a);
  }
  __syncthreads();

  // S7: scale + maxpool2 via lane-pair shuffle, store pvec from registers
#pragma unroll
  for (int n = 0; n < 6; n++) {
    int l = (wv * 6 + n) * 16 + lx;
    float at = xbuf[1544 + l];
    float m[2][4];
#pragma unroll
    for (int mt = 0; mt < 2; mt++)
#pragma unroll
      for (int r = 0; r < 4; r++) {
        float v = a3[n][mt][r] * frq[mt][r] * at;
        m[mt][r] = fmaxf(v, __shfl_xor(v, 1));
      }
    if (!(lx & 1)) {
      int lp = l >> 1;
#pragma unroll
      for (int mt = 0; mt < 2; mt++) {
        uint2v pk;
        pk.x = f2b2(m[mt][0], m[mt][1]);
        pk.y = f2b2(m[mt][2], m[mt][3]);
        *(uint2v*)&pvec[(size_t)b * 12288 + lp * 32 + mt * 16 + quad * 4] = pk;
      }
    }
  }
}

// MLP layer-1 partials (MFMA): block = (32 graphs, 1/4 of K); 512 blocks.
__global__ __launch_bounds__(512) void k_mlp1(
    const unsigned short* __restrict__ pvec, const unsigned short* __restrict__ Wb,
    float* __restrict__ partial) {
  __shared__ float part[8][32][32];
  const int t = threadIdx.x;
  const int lane = t & 63, wv = t >> 6, lx = lane & 15, quad = lane >> 4;
  const int g0 = (blockIdx.x >> 2) * 32;
  const int kc = blockIdx.x & 3;
  const unsigned short* arow0 = pvec + (size_t)(g0 + lx) * 12288 + quad * 8;
  const unsigned short* arow1 = pvec + (size_t)(g0 + 16 + lx) * 12288 + quad * 8;

  f32x4 a00 = {0.f, 0.f, 0.f, 0.f}, a01 = a00, a10 = a00, a11 = a00;
  const int kt0 = kc * 96 + wv * 12;
#pragma unroll 4
  for (int i = 0; i < 12; i++) {
    const int kt = kt0 + i;
    bf16x8 A0 = *(const bf16x8*)&arow0[kt * 32];
    bf16x8 A1 = *(const bf16x8*)&arow1[kt * 32];
    bf16x8 B0 = *(const bf16x8*)&Wb[((kt * 2 + 0) * 64 + lane) * 8];
    bf16x8 B1 = *(const bf16x8*)&Wb[((kt * 2 + 1) * 64 + lane) * 8];
    a00 = __builtin_amdgcn_mfma_f32_16x16x32_bf16(A0, B0, a00, 0, 0, 0);
    a01 = __builtin_amdgcn_mfma_f32_16x16x32_bf16(A0, B1, a01, 0, 0, 0);
    a10 = __builtin_amdgcn_mfma_f32_16x16x32_bf16(A1, B0, a10, 0, 0, 0);
    a11 = __builtin_amdgcn_mfma_f32_16x16x32_bf16(A1, B1, a11, 0, 0, 0);
  }
#pragma unroll
  for (int r = 0; r < 4; r++) {
    part[wv][quad * 4 + r][lx]            = a00[r];
    part[wv][quad * 4 + r][16 + lx]       = a01[r];
    part[wv][16 + quad * 4 + r][lx]       = a10[r];
    part[wv][16 + quad * 4 + r][16 + lx]  = a11[r];
  }
  __syncthreads();
#pragma unroll
  for (int p = 0; p < 2; p++) {
    int idx = t + p * 512;
    int g = idx >> 5, o = idx & 31;
    float s = 0.f;
#pragma unroll
    for (int w = 0; w < 8; w++) s += part[w][g][o];
    partial[((size_t)kc * BB + g0 + g) * 32 + o] = s;
  }
}

// MLP tail
__global__ __launch_bounds__(512) void k_mlp2(
    const float* __restrict__ partial,
    const float* __restrict__ lb1, const float* __restrict__ W2,
    const float* __restrict__ lb2, const float* __restrict__ W3,
    const float* __restrict__ lb3, float* __restrict__ out) {
  __shared__ float s1[16][32];
  __shared__ float s2[16][32];
  const int t = threadIdx.x;
  const int g0 = blockIdx.x * 16;
  {
    int g = t >> 5, o = t & 31;
    float s = lb1[o];
#pragma unroll
    for (int kc = 0; kc < 4; kc++) s += partial[((size_t)kc * BB + g0 + g) * 32 + o];
    s1[g][o] = softplus_(s);
  }
  __syncthreads();
  {
    int g = t >> 5, o = t & 31;
    float s = lb2[o];
    for (int kk = 0; kk < 32; kk++) s += s1[g][kk] * W2[o * 32 + kk];
    s2[g][o] = softplus_(s);
  }
  __syncthreads();
  if (t < 16) {
    float s = lb3[0];
    for (int kk = 0; kk < 32; kk++) s += s2[t][kk] * W3[kk];
    out[g0 + t] = softplus_(s);
  }
}

extern "C" void kernel_launch(void* const* d_in, const int* in_sizes, int n_in,
                              void* d_out, int out_size, void* d_ws, size_t ws_size,
                              hipStream_t stream) {
  const float* drug    = (const float*)d_in[0];
  const int*   ei      = (const int*)d_in[1];
  const float* protein = (const float*)d_in[3];
  const float* g1W = (const float*)d_in[4];
  const float* g1b = (const float*)d_in[5];
  const float* g2W = (const float*)d_in[6];
  const float* g2b = (const float*)d_in[7];
  const float* oW  = (const float*)d_in[8];
  const float* ob  = (const float*)d_in[9];
  const float* c1W = (const float*)d_in[10];
  const float* c1b = (const float*)d_in[11];
  const float* c2W = (const float*)d_in[12];
  const float* c2b = (const float*)d_in[13];
  const float* c3W = (const float*)d_in[14];
  const float* c3b = (const float*)d_in[15];
  const float* caW1 = (const float*)d_in[16];
  const float* caW2 = (const float*)d_in[17];
  const float* samW = (const float*)d_in[18];
  const float* samb = (const float*)d_in[19];
  const float* l1W = (const float*)d_in[20];
  const float* l1b = (const float*)d_in[21];
  const float* l2W = (const float*)d_in[22];
  const float* l2b = (const float*)d_in[23];
  const float* l3W = (const float*)d_in[24];
  const float* l3b = (const float*)d_in[25];

  // ---- workspace map: peak exactly 112 MiB (known-safe) ----
  char* ws = (char*)d_ws;
  float* dinv  = (float*)(ws);                        // [0, 0.5M)
  int*   degi  = (int*)(ws + (size_t)524288);         // [0.5M, 1M)
  int*   cur   = (int*)(ws + (size_t)1048576);        // [1M, 1.5M)
  int*   offs  = (int*)(ws + (size_t)1572864);        // [1.5M, 2M+4)
  int*   bsum  = (int*)(ws + (size_t)2621440);
  int*   bexcl = (int*)(ws + (size_t)2625536);
  int*   csr   = (int*)(ws + (size_t)3145728);        // [3M, 5M)
  unsigned short* gA = (unsigned short*)(ws + (size_t)5242880);   // [5M, 21M)
  unsigned short* gB = (unsigned short*)(ws + (size_t)22020096);  // [21M, 37M)
  unsigned short* pvec = (unsigned short*)(ws + (size_t)5242880); // overlays gA/gB
  float* pooled = (float*)(ws + (size_t)105906176);   // [101M, 103M)
  unsigned short* gout = (unsigned short*)(ws + (size_t)108003328);  // [103M, 109M)
  unsigned short* Wb   = (unsigned short*)(ws + (size_t)114294784);  // 768K
  float* bconst  = (float*)(ws + (size_t)115083136);  // 128 B
  float* edgeK   = (float*)(ws + (size_t)115083264);  // 6144 B
  float* edgeB   = (float*)(ws + (size_t)115089408);  // 512 B
  unsigned short* Kcb = (unsigned short*)(ws + (size_t)115090432); // 2048 B
  unsigned short* Wgb = (unsigned short*)(ws + (size_t)115092480); // 8192 B
  float* partial = (float*)(ws + (size_t)115343360);  // 2 MiB, ends at 112 MiB
  float* outp = (float*)d_out;

  // ---- CSR build + precompute ----
  k_zeroi<<<2 * NN / 256, 256, 0, stream>>>(degi);
  k_hist<<<EE / 256, 256, 0, stream>>>(ei, degi);
  k_scan1<<<NN / 256, 256, 0, stream>>>(degi, offs, bsum);
  k_scan2<<<1, 512, 0, stream>>>(bsum, bexcl);
  k_scan3<<<NN / 256, 256, 0, stream>>>(offs, degi, bexcl, offs, dinv);
  k_scatter<<<EE / 256, 256, 0, stream>>>(ei, offs, cur, csr);
  k_prepw<<<(12288 * 32) / 256, 256, 0, stream>>>(l1W, Wb);
  k_prepg<<<16, 256, 0, stream>>>(g2W, Wgb);
  k_prepk7<<<1, 512, 0, stream>>>(c1W, c1b, c2W, c2b, c3W, c3b, Kcb, bconst);
  k_prepedge<<<26, 64, 0, stream>>>(c1W, c1b, c2W, c2b, c3W, c3b, edgeK, edgeB);

  // ---- GCN ----
  k_mm1<<<NN / 4, 256, 0, stream>>>(drug, g1W, dinv, gA);
  k_layer<true><<<NN / 32, 256, 0, stream>>>(gA, offs, csr, dinv, g1b, Wgb, gB);
  k_layer<true><<<NN / 32, 256, 0, stream>>>(gB, offs, csr, dinv, g2b, Wgb, gA);
  k_lastpool<<<BB, 512, 0, stream>>>(gA, offs, csr, dinv, g2b, pooled);

  // ---- output linear ----
  k_outmm<<<BB / 16, 256, 0, stream>>>(pooled, oW, ob, gout);

  // ---- fused CNN chain (MFMA composite conv) + CBAM + maxpool ----
  k_cnn<<<BB, 512, 0, stream>>>(gout, protein, Kcb, bconst, edgeK, edgeB,
                                caW1, caW2, samW, samb, pvec);

  // ---- MLP head (MFMA, 32 graphs/block, K-split 4x) ----
  k_mlp1<<<(BB / 32) * 4, 512, 0, stream>>>(pvec, Wb, partial);
  k_mlp2<<<BB / 16, 512, 0, stream>>>(partial, l1b, l2W, l2b, l3W, l3b, outp);
}

// Round 14
// 548.301 us; speedup vs baseline: 1.5135x; 1.0600x over previous
//
#include <hip/hip_runtime.h>
#include <cstdint>
#include <cstddef>

#define NN 131072
#define EE 524288
#define BB 4096
#define LL 768

typedef __attribute__((ext_vector_type(8))) short bf16x8;
typedef __attribute__((ext_vector_type(4))) float f32x4;
typedef __attribute__((ext_vector_type(2))) unsigned int uint2v;
typedef __attribute__((ext_vector_type(4))) unsigned int uint4v;

// ---------- helpers ----------
__device__ __forceinline__ float b2f(unsigned short u) {
  return __uint_as_float(((unsigned int)u) << 16);
}
__device__ __forceinline__ unsigned short f2b(float f) {
  unsigned int x = __float_as_uint(f);
  x += 0x7fff + ((x >> 16) & 1);  // RNE
  return (unsigned short)(x >> 16);
}
__device__ __forceinline__ unsigned f2b2(float lo, float hi) {
#if __has_builtin(__builtin_amdgcn_cvt_pk_bf16_f32)
  typedef __attribute__((ext_vector_type(2))) __bf16 bf16v2;
  bf16v2 r = __builtin_amdgcn_cvt_pk_bf16_f32(lo, hi);
  return __builtin_bit_cast(unsigned, r);
#else
  return (unsigned)f2b(lo) | ((unsigned)f2b(hi) << 16);
#endif
}
__device__ __forceinline__ float sigm(float x) { return 1.f / (1.f + expf(-x)); }
__device__ __forceinline__ float softplus_(float x) {
  return fmaxf(x, 0.f) + log1pf(expf(-fabsf(x)));
}

// ---------- CSR build ----------
__global__ __launch_bounds__(256) void k_zeroi(int* __restrict__ p) {
  p[blockIdx.x * 256 + threadIdx.x] = 0;
}
__global__ __launch_bounds__(256) void k_hist(const int* __restrict__ ei,
                                              int* __restrict__ degi) {
  int e = blockIdx.x * 256 + threadIdx.x;
  atomicAdd(&degi[ei[EE + e]], 1);
}
__global__ __launch_bounds__(256) void k_scan1(const int* __restrict__ degi,
                                               int* __restrict__ incl,
                                               int* __restrict__ bsum) {
  __shared__ int s[256];
  int t = threadIdx.x;
  int i = blockIdx.x * 256 + t;
  s[t] = degi[i];
  __syncthreads();
  for (int off = 1; off < 256; off <<= 1) {
    int u = (t >= off) ? s[t - off] : 0;
    __syncthreads();
    s[t] += u;
    __syncthreads();
  }
  incl[i] = s[t];
  if (t == 255) bsum[blockIdx.x] = s[t];
}
__global__ __launch_bounds__(512) void k_scan2(const int* __restrict__ bsum,
                                               int* __restrict__ bexcl) {
  __shared__ int s[512];
  int t = threadIdx.x;
  s[t] = bsum[t];
  __syncthreads();
  int orig = s[t];
  for (int off = 1; off < 512; off <<= 1) {
    int u = (t >= off) ? s[t - off] : 0;
    __syncthreads();
    s[t] += u;
    __syncthreads();
  }
  bexcl[t] = s[t] - orig;
}
__global__ __launch_bounds__(256) void k_scan3(const int* __restrict__ incl,
                                               const int* __restrict__ degi,
                                               const int* __restrict__ bexcl,
                                               int* __restrict__ offs,
                                               float* __restrict__ dinv) {
  int t = threadIdx.x;
  int i = blockIdx.x * 256 + t;
  offs[i] = incl[i] - degi[i] + bexcl[blockIdx.x];
  dinv[i] = rsqrtf((float)degi[i] + 1.0f);
  if (i == 0) offs[NN] = EE;
}
__global__ __launch_bounds__(256) void k_scatter(const int* __restrict__ ei,
                                                 const int* __restrict__ offs,
                                                 int* __restrict__ cur,
                                                 int* __restrict__ csr) {
  int e = blockIdx.x * 256 + threadIdx.x;
  int dst = ei[EE + e];
  int pos = atomicAdd(&cur[dst], 1);
  csr[offs[dst] + pos] = ei[e];
}

// ---------- GCN (bf16 feature buffers) ----------
__global__ __launch_bounds__(256) void k_mm1(const float* __restrict__ drug,
                                             const float* __restrict__ W,
                                             const float* __restrict__ dinv,
                                             unsigned short* __restrict__ g) {
  __shared__ float Ws[9 * 64];
  int t = threadIdx.x;
  for (int i = t; i < 576; i += 256) Ws[i] = W[i];
  __syncthreads();
  int node = blockIdx.x * 4 + (t >> 6);
  int f = t & 63;
  const float* dr = drug + (size_t)node * 9;
  float s = 0.f;
#pragma unroll
  for (int k = 0; k < 9; k++) s += dr[k] * Ws[k * 64 + f];
  g[(size_t)node * 64 + f] = f2b(dinv[node] * s);
}

// Wgb: g2W in MFMA B-fragment order (8 KB)
__global__ __launch_bounds__(256) void k_prepg(const float* __restrict__ W,
                                               unsigned short* __restrict__ Wgb) {
  int idx = blockIdx.x * 256 + threadIdx.x;  // 0..4095
  int j = idx & 7;
  int lane = (idx >> 3) & 63;
  int nt = (idx >> 9) & 3;
  int kc = idx >> 11;
  int k = kc * 32 + (lane >> 4) * 8 + j;
  int o = nt * 16 + (lane & 15);
  Wgb[idx] = f2b(W[k * 64 + o]);
}

// CSR pull aggregation (64 nodes/block, 8 waves) + MFMA 64x64 matmul -> bf16.
template <bool TANH>
__global__ __launch_bounds__(512) void k_layer(const unsigned short* __restrict__ gin,
                                               const int* __restrict__ offs,
                                               const int* __restrict__ csr,
                                               const float* __restrict__ dinv,
                                               const float* __restrict__ bias,
                                               const unsigned short* __restrict__ Wgb,
                                               unsigned short* __restrict__ outb) {
  __shared__ alignas(16) unsigned short xa[64 * 72];  // bf16, stride 72
  __shared__ alignas(16) float dis[64];
  const int t = threadIdx.x;
  const int wv = t >> 6, f = t & 63;
  const int lx = f & 15, quad = f >> 4;
  const int n0 = blockIdx.x * 64;
  const float bf = bias[f];
  // Phase A: aggregate 8 nodes per wave, lane = feature
  for (int it = 0; it < 8; it++) {
    const int dl = wv * 8 + it;
    const int d = n0 + dl;
    const float di = dinv[d];
    const int j0 = offs[d], j1 = offs[d + 1];
    float acc = b2f(gin[(size_t)d * 64 + f]);
    int j = j0;
    for (; j + 4 <= j1; j += 4) {
      int s0 = csr[j], s1 = csr[j + 1], s2 = csr[j + 2], s3 = csr[j + 3];
      acc += (b2f(gin[(size_t)s0 * 64 + f]) + b2f(gin[(size_t)s1 * 64 + f]))
           + (b2f(gin[(size_t)s2 * 64 + f]) + b2f(gin[(size_t)s3 * 64 + f]));
    }
    for (; j < j1; j++) acc += b2f(gin[(size_t)csr[j] * 64 + f]);
    float v = di * acc + bf;
    if (TANH) v = tanhf(v);
    xa[dl * 72 + f] = f2b(v);
    if (f == 0) dis[dl] = di;
  }
  __syncthreads();
  // Phase B: [64x64] @ W[64x64]. wave -> mt = wv>>1 (0..3), np = wv&1
  const int mt = wv >> 1, np = wv & 1;
  bf16x8 A0 = *(const bf16x8*)&xa[(mt * 16 + lx) * 72 + quad * 8];
  bf16x8 A1 = *(const bf16x8*)&xa[(mt * 16 + lx) * 72 + 32 + quad * 8];
  f32x4 accs[2];
#pragma unroll
  for (int nn = 0; nn < 2; nn++) {
    int nt = np * 2 + nn;
    bf16x8 B0 = *(const bf16x8*)&Wgb[((0 * 4 + nt) * 64 + f) * 8];
    bf16x8 B1 = *(const bf16x8*)&Wgb[((1 * 4 + nt) * 64 + f) * 8];
    f32x4 acc = {0.f, 0.f, 0.f, 0.f};
    acc = __builtin_amdgcn_mfma_f32_16x16x32_bf16(A0, B0, acc, 0, 0, 0);
    acc = __builtin_amdgcn_mfma_f32_16x16x32_bf16(A1, B1, acc, 0, 0, 0);
    accs[nn] = acc;
  }
  f32x4 dq = *(const f32x4*)&dis[mt * 16 + quad * 4];
  __syncthreads();  // A-frag reads complete before overwrite
#pragma unroll
  for (int nn = 0; nn < 2; nn++) {
    int nt = np * 2 + nn;
#pragma unroll
    for (int r = 0; r < 4; r++)
      xa[(mt * 16 + quad * 4 + r) * 72 + nt * 16 + lx] = f2b(dq[r] * accs[nn][r]);
  }
  __syncthreads();
  // coalesced writeout: 64 nodes x 8 chunks of 16 B
  {
    int node = t >> 3, c8 = t & 7;
    *(f32x4*)(outb + (size_t)(n0 + node) * 64 + c8 * 8) =
        *(const f32x4*)(xa + node * 72 + c8 * 8);
  }
}

__global__ __launch_bounds__(512) void k_lastpool(const unsigned short* __restrict__ gin,
                                                  const int* __restrict__ offs,
                                                  const int* __restrict__ csr,
                                                  const float* __restrict__ dinv,
                                                  const float* __restrict__ bias,
                                                  float* __restrict__ pooled) {
  __shared__ float smax[8][64], ssum[8][64];
  const int t = threadIdx.x;
  const int f = t & 63, grp = t >> 6;
  const int g = blockIdx.x;
  const float bf = bias[f];
  float mx = -1e30f, sm = 0.f;
#pragma unroll
  for (int i = 0; i < 4; i++) {
    int d = g * 32 + grp * 4 + i;
    const float di = dinv[d];
    const int j0 = offs[d], j1 = offs[d + 1];
    float acc = b2f(gin[(size_t)d * 64 + f]);
    int j = j0;
    for (; j + 4 <= j1; j += 4) {
      int s0 = csr[j], s1 = csr[j + 1], s2 = csr[j + 2], s3 = csr[j + 3];
      acc += (b2f(gin[(size_t)s0 * 64 + f]) + b2f(gin[(size_t)s1 * 64 + f]))
           + (b2f(gin[(size_t)s2 * 64 + f]) + b2f(gin[(size_t)s3 * 64 + f]));
    }
    for (; j < j1; j++) acc += b2f(gin[(size_t)csr[j] * 64 + f]);
    float v = di * acc + bf;
    mx = fmaxf(mx, v);
    sm += v;
  }
  smax[grp][f] = mx;
  ssum[grp][f] = sm;
  __syncthreads();
  if (t < 64) {
    float m = smax[0][t], s = ssum[0][t];
#pragma unroll
    for (int w = 1; w < 8; w++) { m = fmaxf(m, smax[w][t]); s += ssum[w][t]; }
    pooled[(size_t)g * 128 + t] = m;
    pooled[(size_t)g * 128 + 64 + t] = s * (1.f / 32.f);
  }
}

// gout(bf16): 16 graphs/block
__global__ __launch_bounds__(256) void k_outmm(const float* __restrict__ pooled,
                                               const float* __restrict__ W,
                                               const float* __restrict__ bias,
                                               unsigned short* __restrict__ gout) {
  __shared__ float ps[16][128];
  int t = threadIdx.x;
  int g0 = blockIdx.x * 16;
  for (int i = t; i < 16 * 128; i += 256) ps[i >> 7][i & 127] = pooled[(size_t)g0 * 128 + i];
  __syncthreads();
  float a0[16], a1[16], a2[16];
#pragma unroll
  for (int j = 0; j < 16; j++) { a0[j] = 0.f; a1[j] = 0.f; a2[j] = 0.f; }
  for (int k = 0; k < 128; k++) {
    float w0 = W[k * 768 + t];
    float w1 = W[k * 768 + t + 256];
    float w2 = W[k * 768 + t + 512];
#pragma unroll
    for (int j = 0; j < 16; j++) {
      float p = ps[j][k];
      a0[j] += p * w0; a1[j] += p * w1; a2[j] += p * w2;
    }
  }
  float b0 = bias[t], b1 = bias[t + 256], b2 = bias[t + 512];
  for (int j = 0; j < 16; j++) {
    gout[(size_t)(g0 + j) * 768 + t]       = f2b(a0[j] + b0);
    gout[(size_t)(g0 + j) * 768 + t + 256] = f2b(a1[j] + b1);
    gout[(size_t)(g0 + j) * 768 + t + 512] = f2b(a2[j] + b2);
  }
}

// ---------- composite conv precompute (emits bf16 A-frag table) ----------
__global__ __launch_bounds__(512) void k_prepk7(
    const float* __restrict__ W1, const float* __restrict__ b1,
    const float* __restrict__ W2, const float* __restrict__ b2,
    const float* __restrict__ W3, const float* __restrict__ b3,
    unsigned short* __restrict__ Kcb, float* __restrict__ bconst) {
  __shared__ float W1s[192], W2s[3072], W3s[3072];
  __shared__ float b1s[32], b2s[32], b3s[32];
  __shared__ float M[320];
  __shared__ float beta[32];
  __shared__ float KcS[448];
  const int t = threadIdx.x;
  for (int i = t; i < 3072; i += 512) { W2s[i] = W2[i]; W3s[i] = W3[i]; }
  if (t < 192) W1s[t] = W1[t];
  if (t >= 192 && t < 224) { int i = t - 192; b1s[i] = b1[i]; b2s[i] = b2[i]; b3s[i] = b3[i]; }
  __syncthreads();
  if (t < 320) {
    int i = t / 10, rem = t % 10, c = rem / 5, t12 = rem % 5;
    float s = 0.f;
    for (int j = 0; j < 32; j++)
#pragma unroll
      for (int t2 = 0; t2 < 3; t2++) {
        int t1 = t12 - t2;
        if (t1 >= 0 && t1 < 3) s += W2s[(i * 32 + j) * 3 + t2] * W1s[(j * 2 + c) * 3 + t1];
      }
    M[i * 10 + c * 5 + t12] = s;
  }
  if (t >= 384 && t < 416) {
    int i = t - 384;
    float s = b2s[i];
    for (int j = 0; j < 32; j++) {
      float w = W2s[(i * 32 + j) * 3] + W2s[(i * 32 + j) * 3 + 1] + W2s[(i * 32 + j) * 3 + 2];
      s += w * b1s[j];
    }
    beta[i] = s;
  }
  __syncthreads();
  if (t < 448) {
    int o = t / 14, rem = t % 14, c = rem / 7, tt = rem % 7;
    float s = 0.f;
    for (int i = 0; i < 32; i++)
#pragma unroll
      for (int t3 = 0; t3 < 3; t3++) {
        int t12 = tt - t3;
        if (t12 >= 0 && t12 < 5) s += W3s[(o * 32 + i) * 3 + t3] * M[i * 10 + c * 5 + t12];
      }
    KcS[t] = s;
  }
  if (t >= 480 && t < 512) {
    int o = t - 480;
    float s = b3s[o];
    for (int i = 0; i < 32; i++) {
      float w = W3s[(o * 32 + i) * 3] + W3s[(o * 32 + i) * 3 + 1] + W3s[(o * 32 + i) * 3 + 2];
      s += w * beta[i];
    }
    bconst[o] = s;
  }
  __syncthreads();
  for (int i = t; i < 1024; i += 512) {
    int o = i >> 5, k = i & 31;
    Kcb[i] = (k < 14) ? f2b(KcS[o * 14 + k]) : (unsigned short)0;
  }
}

__global__ __launch_bounds__(64) void k_prepedge(
    const float* __restrict__ W1, const float* __restrict__ b1,
    const float* __restrict__ W2, const float* __restrict__ b2,
    const float* __restrict__ W3, const float* __restrict__ b3,
    float* __restrict__ edgeK, float* __restrict__ edgeB) {
  __shared__ float W1s[192], W2s[3072], W3s[3072];
  __shared__ float b1s[32], b2s[32], b3s[32];
  __shared__ float cl[2][6], h1[32][5], h2[32][4];
  const int t = threadIdx.x;
  const int side = blockIdx.x / 13, run = blockIdx.x % 13;
  for (int i = t; i < 3072; i += 64) { W2s[i] = W2[i]; W3s[i] = W3[i]; }
  for (int i = t; i < 192; i += 64) W1s[i] = W1[i];
  if (t < 32) { b1s[t] = b1[t]; b2s[t] = b2[t]; b3s[t] = b3[t]; }
  if (t < 12) cl[t / 6][t % 6] = (run == t) ? 1.f : 0.f;
  __syncthreads();
  const bool ub = (run == 12);
  if (t < 32) {
    int i = t;
    for (int p = 0; p < 5; p++) {
      float s = ub ? b1s[i] : 0.f;
      for (int c = 0; c < 2; c++)
#pragma unroll
        for (int tau = 0; tau < 3; tau++) {
          int x = (side == 0) ? (p + tau - 1) : (p + tau);
          if (x >= 0 && x < 6) s += W1s[(i * 2 + c) * 3 + tau] * cl[c][x];
        }
      h1[i][p] = s;
    }
  }
  __syncthreads();
  if (t < 32) {
    int o = t;
    for (int u = 0; u < 4; u++) {
      float s = ub ? b2s[o] : 0.f;
      for (int i = 0; i < 32; i++)
#pragma unroll
        for (int tau = 0; tau < 3; tau++) {
          int q = (side == 0) ? (u + tau - 1) : (u + tau);
          if (q >= 0 && q < 5) s += W2s[(o * 32 + i) * 3 + tau] * h1[i][q];
        }
      h2[o][u] = s;
    }
  }
  __syncthreads();
  if (t < 32) {
    int o = t;
    for (int e = 0; e < 2; e++) {
      float s = ub ? b3s[o] : 0.f;
      for (int i = 0; i < 32; i++)
#pragma unroll
        for (int tau = 0; tau < 3; tau++) {
          int u = (side == 0) ? (e + tau - 1) : (e + tau + 1);
          if (u >= 0 && u < 4) s += W3s[(o * 32 + i) * 3 + tau] * h2[i][u];
        }
      int slot = (side * 2 + e) * 32 + o;
      if (ub) edgeB[slot] = s;
      else edgeK[slot * 12 + run] = s;
    }
  }
}

// Wb in MFMA B-fragment order, bf16
__global__ __launch_bounds__(256) void k_prepw(const float* __restrict__ W,
                                               unsigned short* __restrict__ Wb) {
  int idx = blockIdx.x * 256 + threadIdx.x;
  int j = idx & 7;
  int lane = (idx >> 3) & 63;
  int nt = (idx >> 9) & 1;
  int kt = idx >> 10;
  int o = nt * 16 + (lane & 15);
  int k = kt * 32 + (lane >> 4) * 8 + j;
  int korig = (k & 31) * 384 + (k >> 5);
  Wb[idx] = f2b(W[(size_t)o * 12288 + korig]);
}

// ---------- persistent fused CNN chain: 16 graphs/block, pipelined input ----------
__global__ __launch_bounds__(512) void k_cnn(
    const unsigned short* __restrict__ gout, const float* __restrict__ protein,
    const unsigned short* __restrict__ Kcb, const float* __restrict__ bconst,
    const float* __restrict__ edgeK, const float* __restrict__ edgeB,
    const float* __restrict__ caW1, const float* __restrict__ caW2,
    const float* __restrict__ samW, const float* __restrict__ samb,
    unsigned short* __restrict__ pvec) {
  __shared__ float combf[1552];                    // input (flat [2][776]); later xm/xM
  __shared__ alignas(16) unsigned short im2[768 * 16];
  __shared__ float attb[768];
  __shared__ float bcs[32];
  __shared__ float wmaxs[8][32], wsums[8][32];
  __shared__ float cmaxs[32], csums[32], t1buf[2][16], feats[32], samWs[8];
  const int t = threadIdx.x;
  const int lane = t & 63, wv = t >> 6, lx = lane & 15, quad = lane >> 4;
  const int bstart = blockIdx.x * 16;

  // static tables (once per persistent block)
  if (t < 32) bcs[t] = bconst[t];
  if (t >= 32 && t < 38) samWs[t - 32] = samW[t - 32];
  if (t == 38) samWs[6] = samb[0];
  __syncthreads();
  bf16x8 A0 = *(const bf16x8*)&Kcb[(0 * 16 + lx) * 32 + quad * 8];
  bf16x8 A1 = *(const bf16x8*)&Kcb[(1 * 16 + lx) * 32 + quad * 8];
  f32x4 ci0, ci1;
#pragma unroll
  for (int r = 0; r < 4; r++) {
    ci0[r] = bcs[quad * 4 + r];
    ci1[r] = bcs[16 + quad * 4 + r];
  }

  // register prefetch of raw input rows: i = t + j*512 over flat 1552
  float rv[3];
#pragma unroll
  for (int j = 0; j < 3; j++) {
    int i = t + j * 512;
    float v = 0.f;
    if (i < 1552) {
      int c = (i >= 776) ? 1 : 0;
      int l = i - c * 776 - 4;
      if (l >= 0 && l < LL)
        v = c ? protein[(size_t)bstart * LL + l] : b2f(gout[(size_t)bstart * LL + l]);
    }
    rv[j] = v;
  }

  for (int gs = 0; gs < 16; gs++) {
    const int b = bstart + gs;
    // stage current graph input to combf
#pragma unroll
    for (int j = 0; j < 3; j++) {
      int i = t + j * 512;
      if (i < 1552) combf[i] = rv[j];
    }
    __syncthreads();
    // prefetch next graph's input (consumed next iteration)
    {
      const int gp = (b + 1 < BB) ? b + 1 : b;
#pragma unroll
      for (int j = 0; j < 3; j++) {
        int i = t + j * 512;
        float v = 0.f;
        if (i < 1552) {
          int c = (i >= 776) ? 1 : 0;
          int l = i - c * 776 - 4;
          if (l >= 0 && l < LL)
            v = c ? protein[(size_t)gp * LL + l] : b2f(gout[(size_t)gp * LL + l]);
        }
        rv[j] = v;
      }
    }

    // S0b: im2col bf16, vectorized b128 writes (items: l in [0,768), half in {0,1})
    for (int p = 0; p < 3; p++) {
      int idx = t + p * 512;  // 0..1535
      int l = idx >> 1, half = idx & 1;
      uint4v pk;
      if (half == 0) {
        // k=0..6: comb[0][l+1..l+7]; k=7: comb[1][l+1]
        float v0 = combf[l + 1], v1 = combf[l + 2], v2 = combf[l + 3], v3 = combf[l + 4];
        float v4 = combf[l + 5], v5 = combf[l + 6], v6 = combf[l + 7];
        float v7 = combf[776 + l + 1];
        pk[0] = f2b2(v0, v1); pk[1] = f2b2(v2, v3);
        pk[2] = f2b2(v4, v5); pk[3] = f2b2(v6, v7);
      } else {
        // k=8..13: comb[1][l+2..l+7]; k=14,15: 0
        float v0 = combf[776 + l + 2], v1 = combf[776 + l + 3], v2 = combf[776 + l + 4];
        float v3 = combf[776 + l + 5], v4 = combf[776 + l + 6], v5 = combf[776 + l + 7];
        pk[0] = f2b2(v0, v1); pk[1] = f2b2(v2, v3);
        pk[2] = f2b2(v4, v5); pk[3] = 0u;
      }
      *(uint4v*)&im2[l * 16 + half * 8] = pk;
    }
    __syncthreads();

    // S1: MFMA conv
    f32x4 a3[6][2];
#pragma unroll
    for (int n = 0; n < 6; n++) {
      int l = (wv * 6 + n) * 16 + lx;
      bf16x8 Bf = {0, 0, 0, 0, 0, 0, 0, 0};
      if (quad < 2) Bf = *(const bf16x8*)&im2[l * 16 + quad * 8];
      a3[n][0] = __builtin_amdgcn_mfma_f32_16x16x32_bf16(A0, Bf, ci0, 0, 0, 0);
      a3[n][1] = __builtin_amdgcn_mfma_f32_16x16x32_bf16(A1, Bf, ci1, 0, 0, 0);
    }
    // edge fixup: l in {0,1} and {766,767}
    {
      bool left = (wv == 0 && lx < 2);
      bool right = (wv == 7 && lx >= 14);
      if (left || right) {
        int n = left ? 0 : 5;
        int e = left ? lx : (lx - 14);
        int side = left ? 0 : 1;
        int cbase = left ? 4 : 766;
#pragma unroll
        for (int mt = 0; mt < 2; mt++)
#pragma unroll
          for (int r = 0; r < 4; r++) {
            int o = mt * 16 + quad * 4 + r;
            int slot = (side * 2 + e) * 32 + o;
            float s = edgeB[slot];
            const float* ek = &edgeK[slot * 12];
#pragma unroll
            for (int w = 0; w < 6; w++)
              s += ek[w] * combf[cbase + w] + ek[6 + w] * combf[776 + cbase + w];
            a3[n][mt][r] = s;
          }
      }
    }

    // S3: channel stats
    float tmax[2][4], tsum[2][4];
#pragma unroll
    for (int mt = 0; mt < 2; mt++)
#pragma unroll
      for (int r = 0; r < 4; r++) { tmax[mt][r] = -1e30f; tsum[mt][r] = 0.f; }
#pragma unroll
    for (int n = 0; n < 6; n++)
#pragma unroll
      for (int mt = 0; mt < 2; mt++)
#pragma unroll
        for (int r = 0; r < 4; r++) {
          float v = a3[n][mt][r];
          tmax[mt][r] = fmaxf(tmax[mt][r], v);
          tsum[mt][r] += v;
        }
#pragma unroll
    for (int mt = 0; mt < 2; mt++)
#pragma unroll
      for (int r = 0; r < 4; r++) {
        float m = tmax[mt][r], s = tsum[mt][r];
        for (int d = 1; d < 16; d <<= 1) {
          m = fmaxf(m, __shfl_xor(m, d));
          s += __shfl_xor(s, d);
        }
        if (lx == 0) {
          wmaxs[wv][mt * 16 + quad * 4 + r] = m;
          wsums[wv][mt * 16 + quad * 4 + r] = s;
        }
      }
    __syncthreads();

    // S4: cross-wave stats + channel-attention MLP
    if (t < 32) {
      float m = wmaxs[0][t], s = wsums[0][t];
#pragma unroll
      for (int w = 1; w < 8; w++) { m = fmaxf(m, wmaxs[w][t]); s += wsums[w][t]; }
      cmaxs[t] = m;
      csums[t] = s;
    }
    __syncthreads();
    if (t < 32) {
      int j = t & 15;
      int mean = t >> 4;
      float s = 0.f;
      for (int o = 0; o < 32; o++) {
        float v = mean ? csums[o] * (1.f / 768.f) : cmaxs[o];
        s += v * caW1[j * 32 + o];
      }
      t1buf[mean][j] = s;
    }
    __syncthreads();
    if (t < 32) {
      float m1 = 0.f, m2 = 0.f;
      for (int j = 0; j < 16; j++) {
        m1 += t1buf[0][j] * caW2[t * 16 + j];
        m2 += t1buf[1][j] * caW2[t * 16 + j];
      }
      feats[t] = sigm(fmaxf(m1, 0.f) + fmaxf(m2, 0.f));
    }
    __syncthreads();

    // S5: spatial stats (xm/xM overlay combf region — input dead after edge fixup)
    float* xmb = combf;
    float* xMb = combf + 772;
    float frq[2][4];
#pragma unroll
    for (int mt = 0; mt < 2; mt++)
#pragma unroll
      for (int r = 0; r < 4; r++) frq[mt][r] = feats[mt * 16 + quad * 4 + r];
#pragma unroll
    for (int n = 0; n < 6; n++) {
      int l = (wv * 6 + n) * 16 + lx;
      float sm = 0.f, mx = -1e30f;
#pragma unroll
      for (int mt = 0; mt < 2; mt++)
#pragma unroll
        for (int r = 0; r < 4; r++) {
          float v = a3[n][mt][r] * frq[mt][r];
          sm += v;
          mx = fmaxf(mx, v);
        }
      sm += __shfl_xor(sm, 16); mx = fmaxf(mx, __shfl_xor(mx, 16));
      sm += __shfl_xor(sm, 32); mx = fmaxf(mx, __shfl_xor(mx, 32));
      if (quad == 0) {
        xmb[l] = sm * (1.f / 32.f);
        xMb[l] = mx;
      }
    }
    __syncthreads();

    // S6: spatial attention conv + sigmoid
    for (int l = t; l < LL; l += 512) {
      float a = samWs[6];
#pragma unroll
      for (int k = 0; k < 3; k++) {
        int ll = l + k - 1;
        float vm = (ll >= 0 && ll < LL) ? xmb[ll] : 0.f;
        float vM = (ll >= 0 && ll < LL) ? xMb[ll] : 0.f;
        a += samWs[k] * vm + samWs[3 + k] * vM;
      }
      attb[l] = sigm(a);
    }
    __syncthreads();

    // S7: scale + maxpool2 via lane-pair shuffle, store pvec from registers
#pragma unroll
    for (int n = 0; n < 6; n++) {
      int l = (wv * 6 + n) * 16 + lx;
      float at = attb[l];
      float m[2][4];
#pragma unroll
      for (int mt = 0; mt < 2; mt++)
#pragma unroll
        for (int r = 0; r < 4; r++) {
          float v = a3[n][mt][r] * frq[mt][r] * at;
          m[mt][r] = fmaxf(v, __shfl_xor(v, 1));
        }
      if (!(lx & 1)) {
        int lp = l >> 1;
#pragma unroll
        for (int mt = 0; mt < 2; mt++) {
          uint2v pk;
          pk.x = f2b2(m[mt][0], m[mt][1]);
          pk.y = f2b2(m[mt][2], m[mt][3]);
          *(uint2v*)&pvec[(size_t)b * 12288 + lp * 32 + mt * 16 + quad * 4] = pk;
        }
      }
    }
    __syncthreads();  // attb/a3 consumed; safe to restage combf next iter
  }
}

// MLP layer-1 partials (MFMA): block = (32 graphs, 1/4 of K); 512 blocks.
__global__ __launch_bounds__(512) void k_mlp1(
    const unsigned short* __restrict__ pvec, const unsigned short* __restrict__ Wb,
    float* __restrict__ partial) {
  __shared__ float part[8][32][32];
  const int t = threadIdx.x;
  const int lane = t & 63, wv = t >> 6, lx = lane & 15, quad = lane >> 4;
  const int g0 = (blockIdx.x >> 2) * 32;
  const int kc = blockIdx.x & 3;
  const unsigned short* arow0 = pvec + (size_t)(g0 + lx) * 12288 + quad * 8;
  const unsigned short* arow1 = pvec + (size_t)(g0 + 16 + lx) * 12288 + quad * 8;

  f32x4 a00 = {0.f, 0.f, 0.f, 0.f}, a01 = a00, a10 = a00, a11 = a00;
  const int kt0 = kc * 96 + wv * 12;
#pragma unroll 4
  for (int i = 0; i < 12; i++) {
    const int kt = kt0 + i;
    bf16x8 A0 = *(const bf16x8*)&arow0[kt * 32];
    bf16x8 A1 = *(const bf16x8*)&arow1[kt * 32];
    bf16x8 B0 = *(const bf16x8*)&Wb[((kt * 2 + 0) * 64 + lane) * 8];
    bf16x8 B1 = *(const bf16x8*)&Wb[((kt * 2 + 1) * 64 + lane) * 8];
    a00 = __builtin_amdgcn_mfma_f32_16x16x32_bf16(A0, B0, a00, 0, 0, 0);
    a01 = __builtin_amdgcn_mfma_f32_16x16x32_bf16(A0, B1, a01, 0, 0, 0);
    a10 = __builtin_amdgcn_mfma_f32_16x16x32_bf16(A1, B0, a10, 0, 0, 0);
    a11 = __builtin_amdgcn_mfma_f32_16x16x32_bf16(A1, B1, a11, 0, 0, 0);
  }
#pragma unroll
  for (int r = 0; r < 4; r++) {
    part[wv][quad * 4 + r][lx]            = a00[r];
    part[wv][quad * 4 + r][16 + lx]       = a01[r];
    part[wv][16 + quad * 4 + r][lx]       = a10[r];
    part[wv][16 + quad * 4 + r][16 + lx]  = a11[r];
  }
  __syncthreads();
#pragma unroll
  for (int p = 0; p < 2; p++) {
    int idx = t + p * 512;
    int g = idx >> 5, o = idx & 31;
    float s = 0.f;
#pragma unroll
    for (int w = 0; w < 8; w++) s += part[w][g][o];
    partial[((size_t)kc * BB + g0 + g) * 32 + o] = s;
  }
}

// MLP tail
__global__ __launch_bounds__(512) void k_mlp2(
    const float* __restrict__ partial,
    const float* __restrict__ lb1, const float* __restrict__ W2,
    const float* __restrict__ lb2, const float* __restrict__ W3,
    const float* __restrict__ lb3, float* __restrict__ out) {
  __shared__ float s1[16][32];
  __shared__ float s2[16][32];
  const int t = threadIdx.x;
  const int g0 = blockIdx.x * 16;
  {
    int g = t >> 5, o = t & 31;
    float s = lb1[o];
#pragma unroll
    for (int kc = 0; kc < 4; kc++) s += partial[((size_t)kc * BB + g0 + g) * 32 + o];
    s1[g][o] = softplus_(s);
  }
  __syncthreads();
  {
    int g = t >> 5, o = t & 31;
    float s = lb2[o];
    for (int kk = 0; kk < 32; kk++) s += s1[g][kk] * W2[o * 32 + kk];
    s2[g][o] = softplus_(s);
  }
  __syncthreads();
  if (t < 16) {
    float s = lb3[0];
    for (int kk = 0; kk < 32; kk++) s += s2[t][kk] * W3[kk];
    out[g0 + t] = softplus_(s);
  }
}

extern "C" void kernel_launch(void* const* d_in, const int* in_sizes, int n_in,
                              void* d_out, int out_size, void* d_ws, size_t ws_size,
                              hipStream_t stream) {
  const float* drug    = (const float*)d_in[0];
  const int*   ei      = (const int*)d_in[1];
  const float* protein = (const float*)d_in[3];
  const float* g1W = (const float*)d_in[4];
  const float* g1b = (const float*)d_in[5];
  const float* g2W = (const float*)d_in[6];
  const float* g2b = (const float*)d_in[7];
  const float* oW  = (const float*)d_in[8];
  const float* ob  = (const float*)d_in[9];
  const float* c1W = (const float*)d_in[10];
  const float* c1b = (const float*)d_in[11];
  const float* c2W = (const float*)d_in[12];
  const float* c2b = (const float*)d_in[13];
  const float* c3W = (const float*)d_in[14];
  const float* c3b = (const float*)d_in[15];
  const float* caW1 = (const float*)d_in[16];
  const float* caW2 = (const float*)d_in[17];
  const float* samW = (const float*)d_in[18];
  const float* samb = (const float*)d_in[19];
  const float* l1W = (const float*)d_in[20];
  const float* l1b = (const float*)d_in[21];
  const float* l2W = (const float*)d_in[22];
  const float* l2b = (const float*)d_in[23];
  const float* l3W = (const float*)d_in[24];
  const float* l3b = (const float*)d_in[25];

  // ---- workspace map: peak exactly 112 MiB (known-safe) ----
  char* ws = (char*)d_ws;
  float* dinv  = (float*)(ws);                        // [0, 0.5M)
  int*   degi  = (int*)(ws + (size_t)524288);         // [0.5M, 1M)
  int*   cur   = (int*)(ws + (size_t)1048576);        // [1M, 1.5M)
  int*   offs  = (int*)(ws + (size_t)1572864);        // [1.5M, 2M+4)
  int*   bsum  = (int*)(ws + (size_t)2621440);
  int*   bexcl = (int*)(ws + (size_t)2625536);
  int*   csr   = (int*)(ws + (size_t)3145728);        // [3M, 5M)
  unsigned short* gA = (unsigned short*)(ws + (size_t)5242880);   // [5M, 21M)
  unsigned short* gB = (unsigned short*)(ws + (size_t)22020096);  // [21M, 37M)
  unsigned short* pvec = (unsigned short*)(ws + (size_t)5242880); // overlays gA/gB
  float* pooled = (float*)(ws + (size_t)105906176);   // [101M, 103M)
  unsigned short* gout = (unsigned short*)(ws + (size_t)108003328);  // [103M, 109M)
  unsigned short* Wb   = (unsigned short*)(ws + (size_t)114294784);  // 768K
  float* bconst  = (float*)(ws + (size_t)115083136);  // 128 B
  float* edgeK   = (float*)(ws + (size_t)115083264);  // 6144 B
  float* edgeB   = (float*)(ws + (size_t)115089408);  // 512 B
  unsigned short* Kcb = (unsigned short*)(ws + (size_t)115090432); // 2048 B
  unsigned short* Wgb = (unsigned short*)(ws + (size_t)115092480); // 8192 B
  float* partial = (float*)(ws + (size_t)115343360);  // 2 MiB, ends at 112 MiB
  float* outp = (float*)d_out;

  // ---- CSR build + precompute ----
  k_zeroi<<<2 * NN / 256, 256, 0, stream>>>(degi);
  k_hist<<<EE / 256, 256, 0, stream>>>(ei, degi);
  k_scan1<<<NN / 256, 256, 0, stream>>>(degi, offs, bsum);
  k_scan2<<<1, 512, 0, stream>>>(bsum, bexcl);
  k_scan3<<<NN / 256, 256, 0, stream>>>(offs, degi, bexcl, offs, dinv);
  k_scatter<<<EE / 256, 256, 0, stream>>>(ei, offs, cur, csr);
  k_prepw<<<(12288 * 32) / 256, 256, 0, stream>>>(l1W, Wb);
  k_prepg<<<16, 256, 0, stream>>>(g2W, Wgb);
  k_prepk7<<<1, 512, 0, stream>>>(c1W, c1b, c2W, c2b, c3W, c3b, Kcb, bconst);
  k_prepedge<<<26, 64, 0, stream>>>(c1W, c1b, c2W, c2b, c3W, c3b, edgeK, edgeB);

  // ---- GCN ----
  k_mm1<<<NN / 4, 256, 0, stream>>>(drug, g1W, dinv, gA);
  k_layer<true><<<NN / 64, 512, 0, stream>>>(gA, offs, csr, dinv, g1b, Wgb, gB);
  k_layer<true><<<NN / 64, 512, 0, stream>>>(gB, offs, csr, dinv, g2b, Wgb, gA);
  k_lastpool<<<BB, 512, 0, stream>>>(gA, offs, csr, dinv, g2b, pooled);

  // ---- output linear ----
  k_outmm<<<BB / 16, 256, 0, stream>>>(pooled, oW, ob, gout);

  // ---- persistent fused CNN chain ----
  k_cnn<<<BB / 16, 512, 0, stream>>>(gout, protein, Kcb, bconst, edgeK, edgeB,
                                     caW1, caW2, samW, samb, pvec);

  // ---- MLP head ----
  k_mlp1<<<(BB / 32) * 4, 512, 0, stream>>>(pvec, Wb, partial);
  k_mlp2<<<BB / 16, 512, 0, stream>>>(partial, l1b, l2W, l2b, l3W, l3b, outp);
}